// Round 2
// baseline (246.502 us; speedup 1.0000x reference)
//
#include <hip/hip_runtime.h>
#include <cstdint>
#include <cstddef>

// Problem constants
#define BSZ   2
#define QL    2048
#define DIMN  640
#define NH    8
#define CMAIN 512
#define AGGD  128
#define MROWS 4096                 // BSZ*QL
#define SCALE_QK 0.11180339887498948f   // (DIM/NHEADS)^-0.5 = 80^-0.5

typedef __bf16 bf16;
typedef __bf16 bf16x8 __attribute__((ext_vector_type(8)));
typedef __bf16 bf16x4v __attribute__((ext_vector_type(4)));
typedef float  f32x4  __attribute__((ext_vector_type(4)));

static __device__ __forceinline__ f32x4 mfma16(bf16x8 a, bf16x8 b, f32x4 c) {
    return __builtin_amdgcn_mfma_f32_16x16x32_bf16(a, b, c, 0, 0, 0);
}

// LDS tiles are [rows][64] bf16 (128 B/row), XOR-swizzled: byte ^= (row&7)<<4
// (breaks the 16-way bank conflict of stride-128B ds_read_b128 columns; G4)
static __device__ __forceinline__ bf16x8 ldsfrag(const bf16* base, int row, int kbyte) {
    return *(const bf16x8*)((const char*)base + row * 128 + (kbyte ^ ((row & 7) << 4)));
}

// stage a 128x64 bf16 tile (row-major src, ld elems/row) into swizzled LDS (256 thr)
static __device__ __forceinline__ void stage128(bf16* lds, const bf16* __restrict__ src,
                                                int row0, int ld, int kk, int tid) {
    #pragma unroll
    for (int i = 0; i < 4; ++i) {
        int e = (tid + i * 256) * 8;          // bf16 element index
        int r = e >> 6, k = e & 63;
        bf16x8 v = *(const bf16x8*)(src + (size_t)(row0 + r) * ld + kk + k);
        *(bf16x8*)((char*)lds + r * 128 + ((k * 2) ^ ((r & 7) << 4))) = v;
    }
}

// Split-bf16 GEMM mainloop. Logical: C = A*B with A (Mx640 fp32) ~ Ahi+Alo,
// B^T given as BThi/BTlo ([n][k] row-major, 640 k per row).
// K' = 1920: seg0 Ahi*Bhi, seg1 Ahi*Blo, seg2 Alo*Bhi (lo*lo dropped, ~2^-18).
// 128x128 tile, 4 waves in 2x2, each wave 64x64 = 4x4 frags of 16x16.
static __device__ __forceinline__ void gemm_main(
    const bf16* __restrict__ Ahi, const bf16* __restrict__ Alo,
    const bf16* __restrict__ BThi, const bf16* __restrict__ BTlo,
    int m0, int n0, bf16* ldsA, bf16* ldsB, f32x4 acc[4][4])
{
    const int tid = threadIdx.x;
    const int w = tid >> 6, lane = tid & 63;
    const int lr = lane & 15, lg = lane >> 4;
    const int wm = (w >> 1) * 64, wn = (w & 1) * 64;

    #pragma unroll 1
    for (int ch = 0; ch < 30; ++ch) {
        int seg = ch / 10;
        int kk = (ch - seg * 10) * 64;
        const bf16* As = (seg < 2) ? Ahi : Alo;
        const bf16* Bs = (seg == 1) ? BTlo : BThi;
        stage128(ldsA, As, m0, 640, kk, tid);
        stage128(ldsB, Bs, n0, 640, kk, tid);
        __syncthreads();
        #pragma unroll
        for (int ks = 0; ks < 2; ++ks) {
            bf16x8 a[4], b[4];
            #pragma unroll
            for (int i = 0; i < 4; ++i) a[i] = ldsfrag(ldsA, wm + i * 16 + lr, ks * 64 + lg * 16);
            #pragma unroll
            for (int i = 0; i < 4; ++i) b[i] = ldsfrag(ldsB, wn + i * 16 + lr, ks * 64 + lg * 16);
            #pragma unroll
            for (int mi = 0; mi < 4; ++mi)
                #pragma unroll
                for (int ni = 0; ni < 4; ++ni)
                    acc[mi][ni] = mfma16(a[mi], b[ni], acc[mi][ni]);
        }
        __syncthreads();
    }
}

// ---- prep: Q (4096x640 f32) -> hi/lo bf16 ----
__global__ void __launch_bounds__(256) k_split_q(const float* __restrict__ Q,
                                                 bf16* __restrict__ Qhi, bf16* __restrict__ Qlo) {
    int i = blockIdx.x * 256 + threadIdx.x;   // 655360 threads, 4 floats each
    float4 v = ((const float4*)Q)[i];
    bf16x4v hv, lv;
    float x;
    x = v.x; hv[0] = (bf16)x; lv[0] = (bf16)(x - (float)hv[0]);
    x = v.y; hv[1] = (bf16)x; lv[1] = (bf16)(x - (float)hv[1]);
    x = v.z; hv[2] = (bf16)x; lv[2] = (bf16)(x - (float)hv[2]);
    x = v.w; hv[3] = (bf16)x; lv[3] = (bf16)(x - (float)hv[3]);
    *(bf16x4v*)(Qhi + (size_t)i * 4) = hv;
    *(bf16x4v*)(Qlo + (size_t)i * 4) = lv;
}

// ---- prep: W_Q|W_K|W_V -> BTqkv[n=1920][k=640] hi/lo ; W_out -> BTout[640][640] hi/lo
__global__ void __launch_bounds__(256) k_prep_w(
    const float* __restrict__ WQ, const float* __restrict__ WK,
    const float* __restrict__ WV, const float* __restrict__ WO,
    bf16* __restrict__ BTqkv_hi, bf16* __restrict__ BTqkv_lo,
    bf16* __restrict__ BTout_hi, bf16* __restrict__ BTout_lo)
{
    int t = blockIdx.x * 256 + threadIdx.x;   // 2560 rows * 160 = 409600 threads
    int n = t / 160;
    int k0 = (t - n * 160) * 4;
    const float* W; bf16 *dh, *dl; int c;
    if (n < 1920) {
        int p = n / 640; c = n - p * 640;
        W = (p == 0) ? WQ : (p == 1) ? WK : WV;
        dh = BTqkv_hi + (size_t)n * 640; dl = BTqkv_lo + (size_t)n * 640;
    } else {
        c = n - 1920; W = WO;
        dh = BTout_hi + (size_t)c * 640; dl = BTout_lo + (size_t)c * 640;
    }
    #pragma unroll
    for (int j = 0; j < 4; ++j) {
        float x = W[(size_t)(k0 + j) * 640 + c];   // B^T[n][k] = W[k][n]
        bf16 h = (bf16)x;
        dh[k0 + j] = h;
        dl[k0 + j] = (bf16)(x - (float)h);
    }
}

// ---- QKV GEMM: C[4096][1920] ; epilogue adds bias (+W_pos for main cols) and routes:
//  cols<512 -> qsbuf[p<2][b][h][l][64] bf16 / vsT[b][h][64][2048] bf16 (p==2, pre-transposed)
//  cols>=512 -> aggbuf[p][4096][128] fp32
__global__ void __launch_bounds__(256) k_gemm_qkv(
    const bf16* __restrict__ Qhi, const bf16* __restrict__ Qlo,
    const bf16* __restrict__ BThi, const bf16* __restrict__ BTlo,
    const float* __restrict__ bQ, const float* __restrict__ bK, const float* __restrict__ bV,
    const float* __restrict__ Wpos,
    bf16* __restrict__ qsbuf, bf16* __restrict__ vsT, float* __restrict__ aggbuf)
{
    __shared__ __align__(16) bf16 ldsA[128 * 64];
    __shared__ __align__(16) bf16 ldsB[128 * 64];
    const int m0 = blockIdx.x * 128, n0 = blockIdx.y * 128;
    f32x4 acc[4][4];
    {
        f32x4 z = {0.f, 0.f, 0.f, 0.f};
        #pragma unroll
        for (int mi = 0; mi < 4; ++mi)
            #pragma unroll
            for (int ni = 0; ni < 4; ++ni) acc[mi][ni] = z;
    }
    gemm_main(Qhi, Qlo, BThi, BTlo, m0, n0, ldsA, ldsB, acc);

    const int tid = threadIdx.x, w = tid >> 6, lane = tid & 63;
    const int lr = lane & 15, lg = lane >> 4;
    const int wm = (w >> 1) * 64, wn = (w & 1) * 64;
    const int p = n0 / 640;                       // block-uniform (640 % 128 == 0)
    const float* bias = (p == 0) ? bQ : (p == 1) ? bK : bV;

    #pragma unroll
    for (int mi = 0; mi < 4; ++mi)
        #pragma unroll
        for (int ni = 0; ni < 4; ++ni) {
            int n = n0 + wn + ni * 16 + lr;
            int c = n - p * 640;
            int rbase = m0 + wm + mi * 16 + lg * 4;
            float bval = bias[c];
            if (c < 512) {
                int hh = c >> 6, d = c & 63;
                #pragma unroll
                for (int r = 0; r < 4; ++r) {
                    int rg = rbase + r;
                    int bb = rg >> 11, l = rg & 2047;
                    float v = acc[mi][ni][r] + bval + Wpos[(size_t)l * 512 + c];
                    if (p < 2)
                        qsbuf[(((size_t)(p * 2 + bb) * 8 + hh) * 2048 + l) * 64 + d] = (bf16)v;
                    else
                        vsT[(((size_t)(bb * 8 + hh)) * 64 + d) * 2048 + l] = (bf16)v;
                }
            } else {
                int j = c - 512;
                #pragma unroll
                for (int r = 0; r < 4; ++r) {
                    int rg = rbase + r;
                    aggbuf[((size_t)p * MROWS + rg) * AGGD + j] = acc[mi][ni][r] + bval;
                }
            }
        }
}

// ---- agg: x = mean3(aggbuf) ; gelu_tanh(x @ W_agg + b_agg) -> xcat cols 512..639 hi/lo
__global__ void __launch_bounds__(256) k_agg(const float* __restrict__ aggbuf,
                                             const float* __restrict__ Wagg, const float* __restrict__ bagg,
                                             bf16* __restrict__ xcat_hi, bf16* __restrict__ xcat_lo)
{
    __shared__ float wl[128 * 128];   // 64 KB
    __shared__ float xl[32 * 128];    // 16 KB
    const int tid = threadIdx.x;
    const int r0 = blockIdx.x * 32;
    for (int i = tid; i < 128 * 128; i += 256) wl[i] = Wagg[i];
    for (int i = tid; i < 32 * 128; i += 256) {
        int row = i >> 7, j = i & 127;
        size_t rg = r0 + row;
        float s = aggbuf[rg * AGGD + j]
                + aggbuf[((size_t)MROWS + rg) * AGGD + j]
                + aggbuf[((size_t)2 * MROWS + rg) * AGGD + j];
        xl[i] = s * (1.0f / 3.0f);
    }
    __syncthreads();
    const int row = tid >> 3;            // 0..31
    const int jo0 = (tid & 7) * 16;      // 16 outputs per thread
    float acc[16];
    #pragma unroll
    for (int jj = 0; jj < 16; ++jj) acc[jj] = 0.f;
    for (int j = 0; j < 128; ++j) {
        float xv = xl[row * 128 + j];
        const float* wr = &wl[j * 128 + jo0];
        #pragma unroll
        for (int jj = 0; jj < 16; ++jj) acc[jj] = fmaf(xv, wr[jj], acc[jj]);
    }
    size_t rg = r0 + row;
    #pragma unroll
    for (int jj = 0; jj < 16; ++jj) {
        float t = acc[jj] + bagg[jo0 + jj];
        float g = 0.5f * t * (1.0f + tanhf(0.7978845608028654f * (t + 0.044715f * t * t * t)));
        bf16 h = (bf16)g;
        size_t o = rg * 640 + 512 + jo0 + jj;
        xcat_hi[o] = h;
        xcat_lo[o] = (bf16)(g - (float)h);
    }
}

// ---- attention: per (b,h, 64-row q-tile); 4 waves x 16 q-rows.
// pass1: exact softmax stats (online max/sum). pass2: recompute S, write normalized
// attn fp32 to d_out, PV with bf16 normalized P -> xcat cols 0..511 hi/lo.
__global__ void __launch_bounds__(256) k_attn(const bf16* __restrict__ qsbuf, const bf16* __restrict__ vsT,
                                              float* __restrict__ gattn,
                                              bf16* __restrict__ xcat_hi, bf16* __restrict__ xcat_lo)
{
    __shared__ __align__(16) bf16 kt_lds[64 * 64];
    __shared__ __align__(16) bf16 vt_lds[64 * 64];
    __shared__ __align__(16) bf16 p_lds[4][16 * 64];

    const int bh = blockIdx.y;
    const int b = bh >> 3, h = bh & 7;
    const int q0 = blockIdx.x * 64;
    const int tid = threadIdx.x, w = tid >> 6, lane = tid & 63;
    const int lr = lane & 15, lg = lane >> 4;

    const bf16* qbase = qsbuf + (size_t)(b * 8 + h) * (2048 * 64);          // p=0
    const bf16* kbase = qsbuf + (size_t)((2 + b) * 8 + h) * (2048 * 64);    // p=1
    const bf16* vtb   = vsT + (size_t)(b * 8 + h) * (64 * 2048);

    bf16x8 aq[2];
    {
        const bf16* qp = qbase + (size_t)(q0 + w * 16 + lr) * 64 + lg * 8;
        aq[0] = *(const bf16x8*)(qp);
        aq[1] = *(const bf16x8*)(qp + 32);
    }

    float mrun[4], lrun[4];
    #pragma unroll
    for (int r = 0; r < 4; ++r) { mrun[r] = -1e30f; lrun[r] = 0.0f; }

    // ---- pass 1: stats
    for (int kt = 0; kt < 32; ++kt) {
        #pragma unroll
        for (int i = 0; i < 2; ++i) {
            int e = (tid + i * 256) * 8;
            int r = e >> 6, k = e & 63;
            bf16x8 v = *(const bf16x8*)(kbase + (size_t)(kt * 64 + r) * 64 + k);
            *(bf16x8*)((char*)kt_lds + r * 128 + ((k * 2) ^ ((r & 7) << 4))) = v;
        }
        __syncthreads();
        f32x4 s[4];
        {
            f32x4 z = {0.f, 0.f, 0.f, 0.f};
            #pragma unroll
            for (int ni = 0; ni < 4; ++ni) s[ni] = z;
        }
        #pragma unroll
        for (int ks = 0; ks < 2; ++ks)
            #pragma unroll
            for (int ni = 0; ni < 4; ++ni)
                s[ni] = mfma16(aq[ks], ldsfrag(kt_lds, ni * 16 + lr, ks * 64 + lg * 16), s[ni]);
        #pragma unroll
        for (int r = 0; r < 4; ++r) {
            float mx = fmaxf(fmaxf(s[0][r], s[1][r]), fmaxf(s[2][r], s[3][r])) * SCALE_QK;
            mx = fmaxf(mx, __shfl_xor(mx, 1));
            mx = fmaxf(mx, __shfl_xor(mx, 2));
            mx = fmaxf(mx, __shfl_xor(mx, 4));
            mx = fmaxf(mx, __shfl_xor(mx, 8));
            float nm = fmaxf(mrun[r], mx);
            float ssum = 0.f;
            #pragma unroll
            for (int ni = 0; ni < 4; ++ni) ssum += __expf(s[ni][r] * SCALE_QK - nm);
            ssum += __shfl_xor(ssum, 1);
            ssum += __shfl_xor(ssum, 2);
            ssum += __shfl_xor(ssum, 4);
            ssum += __shfl_xor(ssum, 8);
            lrun[r] = lrun[r] * __expf(mrun[r] - nm) + ssum;
            mrun[r] = nm;
        }
        __syncthreads();
    }

    float invl[4];
    #pragma unroll
    for (int r = 0; r < 4; ++r) invl[r] = 1.0f / lrun[r];

    f32x4 o[4];
    {
        f32x4 z = {0.f, 0.f, 0.f, 0.f};
        #pragma unroll
        for (int ni = 0; ni < 4; ++ni) o[ni] = z;
    }
    float* attnrow = gattn + (size_t)bh * 2048 * 2048;

    // ---- pass 2: recompute, write attn, PV
    for (int kt = 0; kt < 32; ++kt) {
        #pragma unroll
        for (int i = 0; i < 2; ++i) {
            int e = (tid + i * 256) * 8;
            int r = e >> 6, k = e & 63;
            bf16x8 vk = *(const bf16x8*)(kbase + (size_t)(kt * 64 + r) * 64 + k);
            *(bf16x8*)((char*)kt_lds + r * 128 + ((k * 2) ^ ((r & 7) << 4))) = vk;
            bf16x8 vv = *(const bf16x8*)(vtb + (size_t)r * 2048 + kt * 64 + k);
            *(bf16x8*)((char*)vt_lds + r * 128 + ((k * 2) ^ ((r & 7) << 4))) = vv;
        }
        __syncthreads();
        f32x4 s[4];
        {
            f32x4 z = {0.f, 0.f, 0.f, 0.f};
            #pragma unroll
            for (int ni = 0; ni < 4; ++ni) s[ni] = z;
        }
        #pragma unroll
        for (int ks = 0; ks < 2; ++ks)
            #pragma unroll
            for (int ni = 0; ni < 4; ++ni)
                s[ni] = mfma16(aq[ks], ldsfrag(kt_lds, ni * 16 + lr, ks * 64 + lg * 16), s[ni]);
        #pragma unroll
        for (int ni = 0; ni < 4; ++ni) {
            #pragma unroll
            for (int r = 0; r < 4; ++r) {
                float pv = __expf(s[ni][r] * SCALE_QK - mrun[r]) * invl[r];
                int qr = q0 + w * 16 + lg * 4 + r;
                attnrow[(size_t)qr * 2048 + kt * 64 + ni * 16 + lr] = pv;
                int prow = lg * 4 + r;
                int pb = prow * 128 + (((ni * 16 + lr) * 2) ^ ((prow & 7) << 4));
                *(bf16*)((char*)&p_lds[w][0] + pb) = (bf16)pv;
            }
        }
        __syncthreads();
        #pragma unroll
        for (int ks = 0; ks < 2; ++ks) {
            bf16x8 pa = ldsfrag(&p_lds[w][0], lr, ks * 64 + lg * 16);
            #pragma unroll
            for (int ni = 0; ni < 4; ++ni)
                o[ni] = mfma16(pa, ldsfrag(vt_lds, ni * 16 + lr, ks * 64 + lg * 16), o[ni]);
        }
        __syncthreads();
    }

    #pragma unroll
    for (int ni = 0; ni < 4; ++ni) {
        #pragma unroll
        for (int r = 0; r < 4; ++r) {
            int qr = q0 + w * 16 + lg * 4 + r;
            size_t rg = (size_t)b * 2048 + qr;
            int c = h * 64 + ni * 16 + lr;
            float v = o[ni][r];
            bf16 hv = (bf16)v;
            xcat_hi[rg * 640 + c] = hv;
            xcat_lo[rg * 640 + c] = (bf16)(v - (float)hv);
        }
    }
}

// ---- out GEMM: d_out[0..4096*640) = xcat @ W_out + b_out
__global__ void __launch_bounds__(256) k_gemm_out(
    const bf16* __restrict__ Xhi, const bf16* __restrict__ Xlo,
    const bf16* __restrict__ BThi, const bf16* __restrict__ BTlo,
    const float* __restrict__ bout, float* __restrict__ out0)
{
    __shared__ __align__(16) bf16 ldsA[128 * 64];
    __shared__ __align__(16) bf16 ldsB[128 * 64];
    const int m0 = blockIdx.x * 128, n0 = blockIdx.y * 128;
    f32x4 acc[4][4];
    {
        f32x4 z = {0.f, 0.f, 0.f, 0.f};
        #pragma unroll
        for (int mi = 0; mi < 4; ++mi)
            #pragma unroll
            for (int ni = 0; ni < 4; ++ni) acc[mi][ni] = z;
    }
    gemm_main(Xhi, Xlo, BThi, BTlo, m0, n0, ldsA, ldsB, acc);

    const int tid = threadIdx.x, w = tid >> 6, lane = tid & 63;
    const int lr = lane & 15, lg = lane >> 4;
    const int wm = (w >> 1) * 64, wn = (w & 1) * 64;
    #pragma unroll
    for (int mi = 0; mi < 4; ++mi)
        #pragma unroll
        for (int ni = 0; ni < 4; ++ni) {
            int n = n0 + wn + ni * 16 + lr;
            float bv = bout[n];
            #pragma unroll
            for (int r = 0; r < 4; ++r) {
                int rg = wm + m0 + mi * 16 + lg * 4 + r;
                out0[(size_t)rg * 640 + n] = acc[mi][ni][r] + bv;
            }
        }
}

extern "C" void kernel_launch(void* const* d_in, const int* in_sizes, int n_in,
                              void* d_out, int out_size, void* d_ws, size_t ws_size,
                              hipStream_t stream)
{
    (void)in_sizes; (void)n_in; (void)out_size; (void)ws_size;
    const float* Q    = (const float*)d_in[0];
    const float* WQ   = (const float*)d_in[1];
    const float* bQ   = (const float*)d_in[2];
    const float* WK   = (const float*)d_in[3];
    const float* bK   = (const float*)d_in[4];
    const float* WV   = (const float*)d_in[5];
    const float* bV   = (const float*)d_in[6];
    const float* Wpos = (const float*)d_in[7];
    const float* Wagg = (const float*)d_in[8];
    const float* bagg = (const float*)d_in[9];
    const float* WO   = (const float*)d_in[10];
    const float* bout = (const float*)d_in[11];

    float* out0  = (float*)d_out;
    float* gattn = out0 + (size_t)MROWS * DIMN;   // attn output region (268 MB)

    char* ws = (char*)d_ws;
    bf16* Qhi      = (bf16*)(ws);                 ws += (size_t)MROWS * DIMN * 2;      // 5.24 MB
    bf16* Qlo      = (bf16*)(ws);                 ws += (size_t)MROWS * DIMN * 2;
    bf16* BTqkv_hi = (bf16*)(ws);                 ws += (size_t)1920 * 640 * 2;
    bf16* BTqkv_lo = (bf16*)(ws);                 ws += (size_t)1920 * 640 * 2;
    bf16* BTout_hi = (bf16*)(ws);                 ws += (size_t)640 * 640 * 2;
    bf16* BTout_lo = (bf16*)(ws);                 ws += (size_t)640 * 640 * 2;
    bf16* qsbuf    = (bf16*)(ws);                 ws += (size_t)4 * 8 * 2048 * 64 * 2; // q+k, 2 batches, 8 heads: 8 MB
    bf16* vsT      = (bf16*)(ws);                 ws += (size_t)16 * 64 * 2048 * 2;    // 4 MB
    float* aggbuf  = (float*)(ws);                ws += (size_t)3 * MROWS * AGGD * 4;  // 6 MB
    bf16* xcat_hi  = (bf16*)(ws);                 ws += (size_t)MROWS * DIMN * 2;
    bf16* xcat_lo  = (bf16*)(ws);                 ws += (size_t)MROWS * DIMN * 2;
    // total ~46.4 MB

    k_split_q<<<dim3(2560), dim3(256), 0, stream>>>(Q, Qhi, Qlo);
    k_prep_w<<<dim3(1600), dim3(256), 0, stream>>>(WQ, WK, WV, WO,
                                                   BTqkv_hi, BTqkv_lo, BTout_hi, BTout_lo);
    k_gemm_qkv<<<dim3(32, 15), dim3(256), 0, stream>>>(Qhi, Qlo, BTqkv_hi, BTqkv_lo,
                                                       bQ, bK, bV, Wpos, qsbuf, vsT, aggbuf);
    k_agg<<<dim3(128), dim3(256), 0, stream>>>(aggbuf, Wagg, bagg, xcat_hi, xcat_lo);
    k_attn<<<dim3(32, 16), dim3(256), 0, stream>>>(qsbuf, vsT, gattn, xcat_hi, xcat_lo);
    k_gemm_out<<<dim3(32, 5), dim3(256), 0, stream>>>(xcat_hi, xcat_lo, BTout_hi, BTout_lo,
                                                      bout, out0);
}

// Round 3
// 239.985 us; speedup vs baseline: 1.0272x; 1.0272x over previous
//
#include <hip/hip_runtime.h>
#include <cstdint>
#include <cstddef>

// Problem constants
#define BSZ   2
#define QL    2048
#define DIMN  640
#define NH    8
#define CMAIN 512
#define AGGD  128
#define MROWS 4096                 // BSZ*QL
#define SCALE_QK 0.11180339887498948f   // (DIM/NHEADS)^-0.5 = 80^-0.5

typedef __bf16 bf16;
typedef __bf16 bf16x8 __attribute__((ext_vector_type(8)));
typedef __bf16 bf16x4v __attribute__((ext_vector_type(4)));
typedef float  f32x4  __attribute__((ext_vector_type(4)));

typedef __attribute__((address_space(1))) const uint32_t GU32;
typedef __attribute__((address_space(3))) uint32_t LU32;
#define GLL(g, l) __builtin_amdgcn_global_load_lds((GU32*)(g), (LU32*)(l), 16, 0, 0)

static __device__ __forceinline__ f32x4 mfma16(bf16x8 a, bf16x8 b, f32x4 c) {
    return __builtin_amdgcn_mfma_f32_16x16x32_bf16(a, b, c, 0, 0, 0);
}

// One barrier + one drain per tile. Prefetch loads issued AFTER this point
// overlap the compute phase and are drained at the NEXT call.
static __device__ __forceinline__ void waitbar() {
    asm volatile("s_waitcnt vmcnt(0)" ::: "memory");
    __builtin_amdgcn_s_barrier();
    asm volatile("" ::: "memory");
}

// LDS tiles are [rows][64] bf16 (128 B/row), XOR-swizzled: byte ^= (row&7)<<4.
// global_load_lds writes LDS LINEARLY, so the swizzle is applied by
// inverse-swizzling the per-lane GLOBAL source address (rule #21); the XOR
// flips byte-bit 4 (a whole 16B chunk), so chunks stay contiguous in global.
static __device__ __forceinline__ bf16x8 ldsfrag(const bf16* base, int row, int kbyte) {
    return *(const bf16x8*)((const char*)base + row * 128 + (kbyte ^ ((row & 7) << 4)));
}

// stage a 128x64 bf16 tile (row-major fp-stride 640) via global_load_lds
static __device__ __forceinline__ void stage_tile128(bf16* ldsbuf, const bf16* __restrict__ src,
                                                     int row0, int kk, int tid) {
    const int w = tid >> 6, lane = tid & 63;
    const char* base = (const char*)(src + (size_t)row0 * 640 + kk);
    #pragma unroll
    for (int i = 0; i < 4; ++i) {
        int c = i * 256 + w * 64 + lane;              // 16B chunk index 0..1023
        int r = c >> 3;
        int kb = ((c & 7) * 16) ^ ((r & 7) << 4);     // inverse-swizzled byte-in-row
        GLL(base + (size_t)r * 1280 + kb,
            (char*)ldsbuf + (size_t)(i * 256 + w * 64) * 16);
    }
}

// stage a 64x64 bf16 tile (arbitrary row stride in bytes) via global_load_lds
static __device__ __forceinline__ void stage_tile64(bf16* ldsbuf, const char* gbase,
                                                    int rowStrideB, int tid) {
    const int w = tid >> 6, lane = tid & 63;
    #pragma unroll
    for (int i = 0; i < 2; ++i) {
        int c = i * 256 + w * 64 + lane;              // 0..511
        int r = c >> 3;
        int kb = ((c & 7) * 16) ^ ((r & 7) << 4);
        GLL(gbase + (size_t)r * rowStrideB + kb,
            (char*)ldsbuf + (size_t)(i * 256 + w * 64) * 16);
    }
}

struct SegPtr { const bf16* A; const bf16* B; int kk; };
static __device__ __forceinline__ SegPtr segptr(int ch, const bf16* Ahi, const bf16* Alo,
                                                const bf16* BThi, const bf16* BTlo) {
    int seg = ch / 10;
    SegPtr s;
    s.kk = (ch - seg * 10) * 64;
    s.A = (seg < 2) ? Ahi : Alo;
    s.B = (seg == 1) ? BTlo : BThi;
    return s;
}

// Split-bf16 GEMM mainloop. C = A*B, A (Mx640 fp32) ~ Ahi+Alo, B^T hi/lo [n][k].
// K' = 1920: seg0 Ahi*Bhi, seg1 Ahi*Blo, seg2 Alo*Bhi (lo*lo dropped, ~2^-18).
// 128x128 tile, 4 waves 2x2, each wave 64x64 = 4x4 frags of 16x16x32.
// Double-buffered LDS (64 KB), 1 barrier/chunk, prefetch overlaps compute.
static __device__ __forceinline__ void gemm_main(
    const bf16* __restrict__ Ahi, const bf16* __restrict__ Alo,
    const bf16* __restrict__ BThi, const bf16* __restrict__ BTlo,
    int m0, int n0, bf16* lds, f32x4 acc[4][4])
{
    const int tid = threadIdx.x;
    const int w = tid >> 6, lane = tid & 63;
    const int lr = lane & 15, lg = lane >> 4;
    const int wm = (w >> 1) * 64, wn = (w & 1) * 64;

    {
        SegPtr sp = segptr(0, Ahi, Alo, BThi, BTlo);
        stage_tile128(lds,        sp.A, m0, sp.kk, tid);
        stage_tile128(lds + 8192, sp.B, n0, sp.kk, tid);
    }
    int cur = 0;
    #pragma unroll 1
    for (int ch = 0; ch < 30; ++ch) {
        waitbar();                                   // drain cur's loads; all waves synced
        if (ch < 29) {                               // prefetch next chunk into other buffer
            SegPtr sp = segptr(ch + 1, Ahi, Alo, BThi, BTlo);
            bf16* nb = lds + (cur ^ 1) * 16384;
            stage_tile128(nb,        sp.A, m0, sp.kk, tid);
            stage_tile128(nb + 8192, sp.B, n0, sp.kk, tid);
        }
        const bf16* cA = lds + cur * 16384;
        const bf16* cB = cA + 8192;
        #pragma unroll
        for (int ks = 0; ks < 2; ++ks) {
            bf16x8 a[4], b[4];
            #pragma unroll
            for (int i = 0; i < 4; ++i) a[i] = ldsfrag(cA, wm + i * 16 + lr, ks * 64 + lg * 16);
            #pragma unroll
            for (int i = 0; i < 4; ++i) b[i] = ldsfrag(cB, wn + i * 16 + lr, ks * 64 + lg * 16);
            #pragma unroll
            for (int mi = 0; mi < 4; ++mi)
                #pragma unroll
                for (int ni = 0; ni < 4; ++ni)
                    acc[mi][ni] = mfma16(a[mi], b[ni], acc[mi][ni]);
        }
        cur ^= 1;
    }
}

// ---- prep: Q (4096x640 f32) -> hi/lo bf16 ----
__global__ void __launch_bounds__(256) k_split_q(const float* __restrict__ Q,
                                                 bf16* __restrict__ Qhi, bf16* __restrict__ Qlo) {
    int i = blockIdx.x * 256 + threadIdx.x;
    float4 v = ((const float4*)Q)[i];
    bf16x4v hv, lv;
    float x;
    x = v.x; hv[0] = (bf16)x; lv[0] = (bf16)(x - (float)hv[0]);
    x = v.y; hv[1] = (bf16)x; lv[1] = (bf16)(x - (float)hv[1]);
    x = v.z; hv[2] = (bf16)x; lv[2] = (bf16)(x - (float)hv[2]);
    x = v.w; hv[3] = (bf16)x; lv[3] = (bf16)(x - (float)hv[3]);
    *(bf16x4v*)(Qhi + (size_t)i * 4) = hv;
    *(bf16x4v*)(Qlo + (size_t)i * 4) = lv;
}

// ---- prep: W_Q|W_K|W_V -> BTqkv[n=1920][k=640] hi/lo ; W_out -> BTout[640][640] hi/lo
__global__ void __launch_bounds__(256) k_prep_w(
    const float* __restrict__ WQ, const float* __restrict__ WK,
    const float* __restrict__ WV, const float* __restrict__ WO,
    bf16* __restrict__ BTqkv_hi, bf16* __restrict__ BTqkv_lo,
    bf16* __restrict__ BTout_hi, bf16* __restrict__ BTout_lo)
{
    int t = blockIdx.x * 256 + threadIdx.x;
    int n = t / 160;
    int k0 = (t - n * 160) * 4;
    const float* W; bf16 *dh, *dl; int c;
    if (n < 1920) {
        int p = n / 640; c = n - p * 640;
        W = (p == 0) ? WQ : (p == 1) ? WK : WV;
        dh = BTqkv_hi + (size_t)n * 640; dl = BTqkv_lo + (size_t)n * 640;
    } else {
        c = n - 1920; W = WO;
        dh = BTout_hi + (size_t)c * 640; dl = BTout_lo + (size_t)c * 640;
    }
    #pragma unroll
    for (int j = 0; j < 4; ++j) {
        float x = W[(size_t)(k0 + j) * 640 + c];   // B^T[n][k] = W[k][n]
        bf16 h = (bf16)x;
        dh[k0 + j] = h;
        dl[k0 + j] = (bf16)(x - (float)h);
    }
}

// ---- QKV GEMM: C[4096][1920] ; epilogue adds bias (+W_pos) and routes outputs
__global__ void __launch_bounds__(256) k_gemm_qkv(
    const bf16* __restrict__ Qhi, const bf16* __restrict__ Qlo,
    const bf16* __restrict__ BThi, const bf16* __restrict__ BTlo,
    const float* __restrict__ bQ, const float* __restrict__ bK, const float* __restrict__ bV,
    const float* __restrict__ Wpos,
    bf16* __restrict__ qsbuf, bf16* __restrict__ vsT, float* __restrict__ aggbuf)
{
    __shared__ __align__(16) bf16 ldsAB[4][128 * 64];   // [buf][A/B], 64 KB
    const int m0 = blockIdx.x * 128, n0 = blockIdx.y * 128;
    f32x4 acc[4][4];
    {
        f32x4 z = {0.f, 0.f, 0.f, 0.f};
        #pragma unroll
        for (int mi = 0; mi < 4; ++mi)
            #pragma unroll
            for (int ni = 0; ni < 4; ++ni) acc[mi][ni] = z;
    }
    gemm_main(Qhi, Qlo, BThi, BTlo, m0, n0, &ldsAB[0][0], acc);

    const int tid = threadIdx.x, w = tid >> 6, lane = tid & 63;
    const int lr = lane & 15, lg = lane >> 4;
    const int wm = (w >> 1) * 64, wn = (w & 1) * 64;
    const int p = n0 / 640;                       // block-uniform (640 % 128 == 0)
    const float* bias = (p == 0) ? bQ : (p == 1) ? bK : bV;

    #pragma unroll
    for (int mi = 0; mi < 4; ++mi)
        #pragma unroll
        for (int ni = 0; ni < 4; ++ni) {
            int n = n0 + wn + ni * 16 + lr;
            int c = n - p * 640;
            int rbase = m0 + wm + mi * 16 + lg * 4;
            float bval = bias[c];
            if (c < 512) {
                int hh = c >> 6, d = c & 63;
                #pragma unroll
                for (int r = 0; r < 4; ++r) {
                    int rg = rbase + r;
                    int bb = rg >> 11, l = rg & 2047;
                    float v = acc[mi][ni][r] + bval + Wpos[(size_t)l * 512 + c];
                    if (p < 2)
                        qsbuf[(((size_t)(p * 2 + bb) * 8 + hh) * 2048 + l) * 64 + d] = (bf16)v;
                    else
                        vsT[(((size_t)(bb * 8 + hh)) * 64 + d) * 2048 + l] = (bf16)v;
                }
            } else {
                int j = c - 512;
                #pragma unroll
                for (int r = 0; r < 4; ++r) {
                    int rg = rbase + r;
                    aggbuf[((size_t)p * MROWS + rg) * AGGD + j] = acc[mi][ni][r] + bval;
                }
            }
        }
}

// ---- agg: x = mean3(aggbuf) ; gelu_tanh(x @ W_agg + b_agg) -> xcat cols 512..639
__global__ void __launch_bounds__(256) k_agg(const float* __restrict__ aggbuf,
                                             const float* __restrict__ Wagg, const float* __restrict__ bagg,
                                             bf16* __restrict__ xcat_hi, bf16* __restrict__ xcat_lo)
{
    __shared__ float wl[128 * 128];
    __shared__ float xl[32 * 128];
    const int tid = threadIdx.x;
    const int r0 = blockIdx.x * 32;
    for (int i = tid; i < 128 * 128; i += 256) wl[i] = Wagg[i];
    for (int i = tid; i < 32 * 128; i += 256) {
        int row = i >> 7, j = i & 127;
        size_t rg = r0 + row;
        float s = aggbuf[rg * AGGD + j]
                + aggbuf[((size_t)MROWS + rg) * AGGD + j]
                + aggbuf[((size_t)2 * MROWS + rg) * AGGD + j];
        xl[i] = s * (1.0f / 3.0f);
    }
    __syncthreads();
    const int row = tid >> 3;
    const int jo0 = (tid & 7) * 16;
    float acc[16];
    #pragma unroll
    for (int jj = 0; jj < 16; ++jj) acc[jj] = 0.f;
    for (int j = 0; j < 128; ++j) {
        float xv = xl[row * 128 + j];
        const float* wr = &wl[j * 128 + jo0];
        #pragma unroll
        for (int jj = 0; jj < 16; ++jj) acc[jj] = fmaf(xv, wr[jj], acc[jj]);
    }
    size_t rg = r0 + row;
    #pragma unroll
    for (int jj = 0; jj < 16; ++jj) {
        float t = acc[jj] + bagg[jo0 + jj];
        float g = 0.5f * t * (1.0f + tanhf(0.7978845608028654f * (t + 0.044715f * t * t * t)));
        bf16 h = (bf16)g;
        size_t o = rg * 640 + 512 + jo0 + jj;
        xcat_hi[o] = h;
        xcat_lo[o] = (bf16)(g - (float)h);
    }
}

// ---- attention: per (b,h, 64-row q-tile); 4 waves x 16 q-rows.
// pass1: exact softmax stats. pass2: recompute S, write normalized attn fp32,
// PV -> xcat cols 0..511 hi/lo. Both passes double-buffered, 1 barrier/tile.
__global__ void __launch_bounds__(256) k_attn(const bf16* __restrict__ qsbuf, const bf16* __restrict__ vsT,
                                              float* __restrict__ gattn,
                                              bf16* __restrict__ xcat_hi, bf16* __restrict__ xcat_lo)
{
    __shared__ __align__(16) bf16 kbuf[2][64 * 64];     // 16 KB
    __shared__ __align__(16) bf16 vbuf[2][64 * 64];     // 16 KB
    __shared__ __align__(16) bf16 p_lds[4][16 * 64];    // 8 KB, per-wave private

    const int bh = blockIdx.y;
    const int b = bh >> 3, h = bh & 7;
    const int q0 = blockIdx.x * 64;
    const int tid = threadIdx.x, w = tid >> 6, lane = tid & 63;
    const int lr = lane & 15, lg = lane >> 4;

    const bf16* qbase = qsbuf + (size_t)(b * 8 + h) * (2048 * 64);          // p=0
    const bf16* kbase = qsbuf + (size_t)((2 + b) * 8 + h) * (2048 * 64);    // p=1
    const bf16* vtb   = vsT + (size_t)(b * 8 + h) * (64 * 2048);

    bf16x8 aq[2];
    {
        const bf16* qp = qbase + (size_t)(q0 + w * 16 + lr) * 64 + lg * 8;
        aq[0] = *(const bf16x8*)(qp);
        aq[1] = *(const bf16x8*)(qp + 32);
    }

    float mrun[4], lrun[4];
    #pragma unroll
    for (int r = 0; r < 4; ++r) { mrun[r] = -1e30f; lrun[r] = 0.0f; }

    // ---- pass 1: stats (K double-buffered)
    stage_tile64(kbuf[0], (const char*)kbase, 128, tid);
    int cur = 0;
    #pragma unroll 1
    for (int kt = 0; kt < 32; ++kt) {
        waitbar();
        if (kt < 31)
            stage_tile64(kbuf[cur ^ 1], (const char*)(kbase + (size_t)(kt + 1) * 64 * 64), 128, tid);
        f32x4 s[4];
        {
            f32x4 z = {0.f, 0.f, 0.f, 0.f};
            #pragma unroll
            for (int ni = 0; ni < 4; ++ni) s[ni] = z;
        }
        #pragma unroll
        for (int ks = 0; ks < 2; ++ks)
            #pragma unroll
            for (int ni = 0; ni < 4; ++ni)
                s[ni] = mfma16(aq[ks], ldsfrag(kbuf[cur], ni * 16 + lr, ks * 64 + lg * 16), s[ni]);
        #pragma unroll
        for (int r = 0; r < 4; ++r) {
            float mx = fmaxf(fmaxf(s[0][r], s[1][r]), fmaxf(s[2][r], s[3][r])) * SCALE_QK;
            mx = fmaxf(mx, __shfl_xor(mx, 1));
            mx = fmaxf(mx, __shfl_xor(mx, 2));
            mx = fmaxf(mx, __shfl_xor(mx, 4));
            mx = fmaxf(mx, __shfl_xor(mx, 8));
            float nm = fmaxf(mrun[r], mx);
            float ssum = 0.f;
            #pragma unroll
            for (int ni = 0; ni < 4; ++ni) ssum += __expf(s[ni][r] * SCALE_QK - nm);
            ssum += __shfl_xor(ssum, 1);
            ssum += __shfl_xor(ssum, 2);
            ssum += __shfl_xor(ssum, 4);
            ssum += __shfl_xor(ssum, 8);
            lrun[r] = lrun[r] * __expf(mrun[r] - nm) + ssum;
            mrun[r] = nm;
        }
        cur ^= 1;
    }
    __syncthreads();   // all waves done with kbuf before pass-2 prologue overwrites

    float invl[4];
    #pragma unroll
    for (int r = 0; r < 4; ++r) invl[r] = 1.0f / lrun[r];

    f32x4 o[4];
    {
        f32x4 z = {0.f, 0.f, 0.f, 0.f};
        #pragma unroll
        for (int ni = 0; ni < 4; ++ni) o[ni] = z;
    }
    float* attnrow = gattn + (size_t)bh * 2048 * 2048;

    // ---- pass 2: recompute, write attn, PV (K+V double-buffered)
    stage_tile64(kbuf[0], (const char*)kbase, 128, tid);
    stage_tile64(vbuf[0], (const char*)vtb, 4096, tid);
    cur = 0;
    #pragma unroll 1
    for (int kt = 0; kt < 32; ++kt) {
        waitbar();
        if (kt < 31) {
            stage_tile64(kbuf[cur ^ 1], (const char*)(kbase + (size_t)(kt + 1) * 64 * 64), 128, tid);
            stage_tile64(vbuf[cur ^ 1], (const char*)vtb + (size_t)(kt + 1) * 128, 4096, tid);
        }
        f32x4 s[4];
        {
            f32x4 z = {0.f, 0.f, 0.f, 0.f};
            #pragma unroll
            for (int ni = 0; ni < 4; ++ni) s[ni] = z;
        }
        #pragma unroll
        for (int ks = 0; ks < 2; ++ks)
            #pragma unroll
            for (int ni = 0; ni < 4; ++ni)
                s[ni] = mfma16(aq[ks], ldsfrag(kbuf[cur], ni * 16 + lr, ks * 64 + lg * 16), s[ni]);
        #pragma unroll
        for (int ni = 0; ni < 4; ++ni) {
            #pragma unroll
            for (int r = 0; r < 4; ++r) {
                float pv = __expf(s[ni][r] * SCALE_QK - mrun[r]) * invl[r];
                int qr = q0 + w * 16 + lg * 4 + r;
                attnrow[(size_t)qr * 2048 + kt * 64 + ni * 16 + lr] = pv;
                int prow = lg * 4 + r;
                int pb = prow * 128 + (((ni * 16 + lr) * 2) ^ ((prow & 7) << 4));
                *(bf16*)((char*)&p_lds[w][0] + pb) = (bf16)pv;
            }
        }
        // p_lds[w] is wave-private: same-wave ds_write->ds_read needs only
        // lgkmcnt (compiler-inserted); no barrier.
        #pragma unroll
        for (int ks = 0; ks < 2; ++ks) {
            bf16x8 pa = ldsfrag(&p_lds[w][0], lr, ks * 64 + lg * 16);
            #pragma unroll
            for (int ni = 0; ni < 4; ++ni)
                o[ni] = mfma16(pa, ldsfrag(vbuf[cur], ni * 16 + lr, ks * 64 + lg * 16), o[ni]);
        }
        cur ^= 1;
    }

    #pragma unroll
    for (int ni = 0; ni < 4; ++ni) {
        #pragma unroll
        for (int r = 0; r < 4; ++r) {
            int qr = q0 + w * 16 + lg * 4 + r;
            size_t rg = (size_t)b * 2048 + qr;
            int c = h * 64 + ni * 16 + lr;
            float v = o[ni][r];
            bf16 hv = (bf16)v;
            xcat_hi[rg * 640 + c] = hv;
            xcat_lo[rg * 640 + c] = (bf16)(v - (float)hv);
        }
    }
}

// ---- out GEMM: d_out[0..4096*640) = xcat @ W_out + b_out
__global__ void __launch_bounds__(256) k_gemm_out(
    const bf16* __restrict__ Xhi, const bf16* __restrict__ Xlo,
    const bf16* __restrict__ BThi, const bf16* __restrict__ BTlo,
    const float* __restrict__ bout, float* __restrict__ out0)
{
    __shared__ __align__(16) bf16 ldsAB[4][128 * 64];
    const int m0 = blockIdx.x * 128, n0 = blockIdx.y * 128;
    f32x4 acc[4][4];
    {
        f32x4 z = {0.f, 0.f, 0.f, 0.f};
        #pragma unroll
        for (int mi = 0; mi < 4; ++mi)
            #pragma unroll
            for (int ni = 0; ni < 4; ++ni) acc[mi][ni] = z;
    }
    gemm_main(Xhi, Xlo, BThi, BTlo, m0, n0, &ldsAB[0][0], acc);

    const int tid = threadIdx.x, w = tid >> 6, lane = tid & 63;
    const int lr = lane & 15, lg = lane >> 4;
    const int wm = (w >> 1) * 64, wn = (w & 1) * 64;
    #pragma unroll
    for (int mi = 0; mi < 4; ++mi)
        #pragma unroll
        for (int ni = 0; ni < 4; ++ni) {
            int n = n0 + wn + ni * 16 + lr;
            float bv = bout[n];
            #pragma unroll
            for (int r = 0; r < 4; ++r) {
                int rg = wm + m0 + mi * 16 + lg * 4 + r;
                out0[(size_t)rg * 640 + n] = acc[mi][ni][r] + bv;
            }
        }
}

extern "C" void kernel_launch(void* const* d_in, const int* in_sizes, int n_in,
                              void* d_out, int out_size, void* d_ws, size_t ws_size,
                              hipStream_t stream)
{
    (void)in_sizes; (void)n_in; (void)out_size; (void)ws_size;
    const float* Q    = (const float*)d_in[0];
    const float* WQ   = (const float*)d_in[1];
    const float* bQ   = (const float*)d_in[2];
    const float* WK   = (const float*)d_in[3];
    const float* bK   = (const float*)d_in[4];
    const float* WV   = (const float*)d_in[5];
    const float* bV   = (const float*)d_in[6];
    const float* Wpos = (const float*)d_in[7];
    const float* Wagg = (const float*)d_in[8];
    const float* bagg = (const float*)d_in[9];
    const float* WO   = (const float*)d_in[10];
    const float* bout = (const float*)d_in[11];

    float* out0  = (float*)d_out;
    float* gattn = out0 + (size_t)MROWS * DIMN;   // attn output region (268 MB)

    char* ws = (char*)d_ws;
    bf16* Qhi      = (bf16*)(ws);                 ws += (size_t)MROWS * DIMN * 2;
    bf16* Qlo      = (bf16*)(ws);                 ws += (size_t)MROWS * DIMN * 2;
    bf16* BTqkv_hi = (bf16*)(ws);                 ws += (size_t)1920 * 640 * 2;
    bf16* BTqkv_lo = (bf16*)(ws);                 ws += (size_t)1920 * 640 * 2;
    bf16* BTout_hi = (bf16*)(ws);                 ws += (size_t)640 * 640 * 2;
    bf16* BTout_lo = (bf16*)(ws);                 ws += (size_t)640 * 640 * 2;
    bf16* qsbuf    = (bf16*)(ws);                 ws += (size_t)4 * 8 * 2048 * 64 * 2; // 8 MB
    bf16* vsT      = (bf16*)(ws);                 ws += (size_t)16 * 64 * 2048 * 2;    // 4 MB
    float* aggbuf  = (float*)(ws);                ws += (size_t)3 * MROWS * AGGD * 4;  // 6 MB
    bf16* xcat_hi  = (bf16*)(ws);                 ws += (size_t)MROWS * DIMN * 2;
    bf16* xcat_lo  = (bf16*)(ws);                 ws += (size_t)MROWS * DIMN * 2;

    k_split_q<<<dim3(2560), dim3(256), 0, stream>>>(Q, Qhi, Qlo);
    k_prep_w<<<dim3(1600), dim3(256), 0, stream>>>(WQ, WK, WV, WO,
                                                   BTqkv_hi, BTqkv_lo, BTout_hi, BTout_lo);
    k_gemm_qkv<<<dim3(32, 15), dim3(256), 0, stream>>>(Qhi, Qlo, BTqkv_hi, BTqkv_lo,
                                                       bQ, bK, bV, Wpos, qsbuf, vsT, aggbuf);
    k_agg<<<dim3(128), dim3(256), 0, stream>>>(aggbuf, Wagg, bagg, xcat_hi, xcat_lo);
    k_attn<<<dim3(32, 16), dim3(256), 0, stream>>>(qsbuf, vsT, gattn, xcat_hi, xcat_lo);
    k_gemm_out<<<dim3(32, 5), dim3(256), 0, stream>>>(xcat_hi, xcat_lo, BTout_hi, BTout_lo,
                                                      bout, out0);
}

// Round 4
// 205.648 us; speedup vs baseline: 1.1987x; 1.1670x over previous
//
#include <hip/hip_runtime.h>
#include <cstdint>
#include <cstddef>

// Problem constants
#define BSZ   2
#define QL    2048
#define DIMN  640
#define NH    8
#define CMAIN 512
#define AGGD  128
#define MROWS 4096                 // BSZ*QL
#define SCALE_QK 0.11180339887498948f   // (DIM/NHEADS)^-0.5 = 80^-0.5

typedef __bf16 bf16;
typedef __bf16 bf16x8 __attribute__((ext_vector_type(8)));
typedef __bf16 bf16x4v __attribute__((ext_vector_type(4)));
typedef float  f32x4  __attribute__((ext_vector_type(4)));

typedef __attribute__((address_space(1))) const uint32_t GU32;
typedef __attribute__((address_space(3))) uint32_t LU32;
#define GLL(g, l) __builtin_amdgcn_global_load_lds((GU32*)(g), (LU32*)(l), 16, 0, 0)

static __device__ __forceinline__ f32x4 mfma16(bf16x8 a, bf16x8 b, f32x4 c) {
    return __builtin_amdgcn_mfma_f32_16x16x32_bf16(a, b, c, 0, 0, 0);
}

static __device__ __forceinline__ void waitbar() {
    asm volatile("s_waitcnt vmcnt(0)" ::: "memory");
    __builtin_amdgcn_s_barrier();
    asm volatile("" ::: "memory");
}

// LDS tiles are [rows][64] bf16 (128 B/row), XOR-swizzled: byte ^= (row&7)<<4.
// global_load_lds writes LDS linearly, so the swizzle is applied by
// inverse-swizzling the per-lane GLOBAL source address (both-sides rule #21).
static __device__ __forceinline__ bf16x8 ldsfrag(const bf16* base, int row, int kbyte) {
    return *(const bf16x8*)((const char*)base + row * 128 + (kbyte ^ ((row & 7) << 4)));
}

// stage NCH 16B-chunks (= NCH/8 rows of 128B) from rows of `strideB` bytes.
// 256 threads. LDS dest is wave-uniform base; HW appends lane*16.
template<int NCH>
static __device__ __forceinline__ void stage_rows(bf16* ldsbuf, const char* gbase,
                                                  int strideB, int tid) {
    const int w = tid >> 6, lane = tid & 63;
    #pragma unroll
    for (int i = 0; i < NCH / 256; ++i) {
        int c = i * 256 + w * 64 + lane;
        int r = c >> 3;
        int kb = ((c & 7) * 16) ^ ((r & 7) << 4);     // inverse-swizzled byte-in-row
        GLL(gbase + (size_t)r * strideB + kb,
            (char*)ldsbuf + (size_t)(i * 256 + w * 64) * 16);
    }
}

struct SegPtr { const bf16* A; const bf16* B; int kk; };
static __device__ __forceinline__ SegPtr segptr(int ch, const bf16* Ahi, const bf16* Alo,
                                                const bf16* BThi, const bf16* BTlo) {
    int seg = ch / 10;
    SegPtr s;
    s.kk = (ch - seg * 10) * 64;
    s.A = (seg < 2) ? Ahi : Alo;
    s.B = (seg == 1) ? BTlo : BThi;
    return s;
}

// Split-bf16 GEMM mainloop. C = A*B, A (Mx640 fp32) ~ Ahi+Alo, B^T hi/lo [n][k].
// K' = 1920: seg0 Ahi*Bhi, seg1 Ahi*Blo, seg2 Alo*Bhi (lo*lo dropped, ~2^-18).
// Block tile (MI*32)x128, 4 waves 2x2, wave tile (MI*16)x64. Double-buffered.
template<int MI>
static __device__ __forceinline__ void gemm_main(
    const bf16* __restrict__ Ahi, const bf16* __restrict__ Alo,
    const bf16* __restrict__ BThi, const bf16* __restrict__ BTlo,
    int m0, int n0, bf16* lds, f32x4 acc[MI][4])
{
    const int tid = threadIdx.x;
    const int w = tid >> 6, lane = tid & 63;
    const int lr = lane & 15, lg = lane >> 4;
    const int wm = (w >> 1) * (MI * 16), wn = (w & 1) * 64;
    constexpr int ASZ = MI * 2048;          // A-tile bf16 elems (MI*32 rows)
    constexpr int BUF = ASZ + 8192;

    {
        SegPtr sp = segptr(0, Ahi, Alo, BThi, BTlo);
        stage_rows<MI * 256>(lds,     (const char*)(sp.A + (size_t)m0 * 640 + sp.kk), 1280, tid);
        stage_rows<1024>(lds + ASZ,   (const char*)(sp.B + (size_t)n0 * 640 + sp.kk), 1280, tid);
    }
    int cur = 0;
    #pragma unroll 1
    for (int ch = 0; ch < 30; ++ch) {
        waitbar();                                   // drain cur's loads; all waves synced
        if (ch < 29) {
            SegPtr sp = segptr(ch + 1, Ahi, Alo, BThi, BTlo);
            bf16* nb = lds + (cur ^ 1) * BUF;
            stage_rows<MI * 256>(nb,   (const char*)(sp.A + (size_t)m0 * 640 + sp.kk), 1280, tid);
            stage_rows<1024>(nb + ASZ, (const char*)(sp.B + (size_t)n0 * 640 + sp.kk), 1280, tid);
        }
        const bf16* cA = lds + cur * BUF;
        const bf16* cB = cA + ASZ;
        #pragma unroll
        for (int ks = 0; ks < 2; ++ks) {
            bf16x8 a[MI], b[4];
            #pragma unroll
            for (int i = 0; i < MI; ++i) a[i] = ldsfrag(cA, wm + i * 16 + lr, ks * 64 + lg * 16);
            #pragma unroll
            for (int i = 0; i < 4; ++i)  b[i] = ldsfrag(cB, wn + i * 16 + lr, ks * 64 + lg * 16);
            #pragma unroll
            for (int mi = 0; mi < MI; ++mi)
                #pragma unroll
                for (int ni = 0; ni < 4; ++ni)
                    acc[mi][ni] = mfma16(a[mi], b[ni], acc[mi][ni]);
        }
        cur ^= 1;
    }
}

// ---- prep: Q (4096x640 f32) -> hi/lo bf16 ----
__global__ void __launch_bounds__(256) k_split_q(const float* __restrict__ Q,
                                                 bf16* __restrict__ Qhi, bf16* __restrict__ Qlo) {
    int i = blockIdx.x * 256 + threadIdx.x;
    float4 v = ((const float4*)Q)[i];
    bf16x4v hv, lv;
    float x;
    x = v.x; hv[0] = (bf16)x; lv[0] = (bf16)(x - (float)hv[0]);
    x = v.y; hv[1] = (bf16)x; lv[1] = (bf16)(x - (float)hv[1]);
    x = v.z; hv[2] = (bf16)x; lv[2] = (bf16)(x - (float)hv[2]);
    x = v.w; hv[3] = (bf16)x; lv[3] = (bf16)(x - (float)hv[3]);
    *(bf16x4v*)(Qhi + (size_t)i * 4) = hv;
    *(bf16x4v*)(Qlo + (size_t)i * 4) = lv;
}

// ---- prep: coalesced LDS-transpose of W_Q/W_K/W_V/W_out into B^T hi/lo.
// grid (100, 4): 64x64 tile (tx=k-tile, ty=n-tile), y selects the matrix.
__global__ void __launch_bounds__(256) k_prep_w(
    const float* __restrict__ WQ, const float* __restrict__ WK,
    const float* __restrict__ WV, const float* __restrict__ WO,
    bf16* __restrict__ BTqkv_hi, bf16* __restrict__ BTqkv_lo,
    bf16* __restrict__ BTout_hi, bf16* __restrict__ BTout_lo)
{
    __shared__ float tl[64][65];     // tl[n_loc][k_loc]
    const int ty = blockIdx.x / 10, tx = blockIdx.x % 10;
    const int wsel = blockIdx.y;
    const float* W = (wsel == 0) ? WQ : (wsel == 1) ? WK : (wsel == 2) ? WV : WO;
    const int tid = threadIdx.x;
    const int rr = tid >> 4;             // k row group 0..15
    const int cc = (tid & 15) * 4;       // n col 0..60
    #pragma unroll
    for (int i = 0; i < 4; ++i) {
        int k = tx * 64 + rr + i * 16;
        float4 v = *(const float4*)(W + (size_t)k * 640 + ty * 64 + cc);
        tl[cc + 0][rr + i * 16] = v.x;
        tl[cc + 1][rr + i * 16] = v.y;
        tl[cc + 2][rr + i * 16] = v.z;
        tl[cc + 3][rr + i * 16] = v.w;
    }
    __syncthreads();
    bf16 *dh, *dl; int nbase;
    if (wsel < 3) { dh = BTqkv_hi; dl = BTqkv_lo; nbase = wsel * 640 + ty * 64; }
    else          { dh = BTout_hi; dl = BTout_lo; nbase = ty * 64; }
    const int nl0 = tid >> 4;
    const int kl = (tid & 15) * 4;
    #pragma unroll
    for (int i = 0; i < 4; ++i) {
        int nl = nl0 + i * 16;
        bf16x4v hv, lv;
        #pragma unroll
        for (int j = 0; j < 4; ++j) {
            float x = tl[nl][kl + j];
            bf16 h = (bf16)x;
            hv[j] = h; lv[j] = (bf16)(x - (float)h);
        }
        size_t o = (size_t)(nbase + nl) * 640 + tx * 64 + kl;
        *(bf16x4v*)(dh + o) = hv;
        *(bf16x4v*)(dl + o) = lv;
    }
}

// ---- QKV GEMM: C[4096][1920] ; epilogue adds bias (+W_pos) and routes outputs
__global__ void __launch_bounds__(256) k_gemm_qkv(
    const bf16* __restrict__ Qhi, const bf16* __restrict__ Qlo,
    const bf16* __restrict__ BThi, const bf16* __restrict__ BTlo,
    const float* __restrict__ bQ, const float* __restrict__ bK, const float* __restrict__ bV,
    const float* __restrict__ Wpos,
    bf16* __restrict__ qsbuf, bf16* __restrict__ vsT, float* __restrict__ aggbuf)
{
    __shared__ __align__(16) bf16 lds[2 * (8192 + 8192)];   // 64 KB
    const int m0 = blockIdx.x * 128, n0 = blockIdx.y * 128;
    f32x4 acc[4][4];
    {
        f32x4 z = {0.f, 0.f, 0.f, 0.f};
        #pragma unroll
        for (int mi = 0; mi < 4; ++mi)
            #pragma unroll
            for (int ni = 0; ni < 4; ++ni) acc[mi][ni] = z;
    }
    gemm_main<4>(Qhi, Qlo, BThi, BTlo, m0, n0, lds, acc);

    const int tid = threadIdx.x, w = tid >> 6, lane = tid & 63;
    const int lr = lane & 15, lg = lane >> 4;
    const int wm = (w >> 1) * 64, wn = (w & 1) * 64;
    const int p = n0 / 640;                       // block-uniform (640 % 128 == 0)
    const float* bias = (p == 0) ? bQ : (p == 1) ? bK : bV;

    #pragma unroll
    for (int mi = 0; mi < 4; ++mi)
        #pragma unroll
        for (int ni = 0; ni < 4; ++ni) {
            int n = n0 + wn + ni * 16 + lr;
            int c = n - p * 640;
            int rbase = m0 + wm + mi * 16 + lg * 4;
            float bval = bias[c];
            if (c < 512) {
                int hh = c >> 6, d = c & 63;
                #pragma unroll
                for (int r = 0; r < 4; ++r) {
                    int rg = rbase + r;
                    int bb = rg >> 11, l = rg & 2047;
                    float v = acc[mi][ni][r] + bval + Wpos[(size_t)l * 512 + c];
                    if (p < 2)
                        qsbuf[(((size_t)(p * 2 + bb) * 8 + hh) * 2048 + l) * 64 + d] = (bf16)v;
                    else
                        vsT[(((size_t)(bb * 8 + hh)) * 64 + d) * 2048 + l] = (bf16)v;
                }
            } else {
                int j = c - 512;
                #pragma unroll
                for (int r = 0; r < 4; ++r) {
                    int rg = rbase + r;
                    aggbuf[((size_t)p * MROWS + rg) * AGGD + j] = acc[mi][ni][r] + bval;
                }
            }
        }
}

// ---- agg: x = mean3(aggbuf) ; gelu_tanh(x @ W_agg + b_agg) -> xcat cols 512..639
__global__ void __launch_bounds__(256) k_agg(const float* __restrict__ aggbuf,
                                             const float* __restrict__ Wagg, const float* __restrict__ bagg,
                                             bf16* __restrict__ xcat_hi, bf16* __restrict__ xcat_lo)
{
    __shared__ float wl[128 * 128];
    __shared__ float xl[32 * 128];
    const int tid = threadIdx.x;
    const int r0 = blockIdx.x * 32;
    for (int i = tid; i < 128 * 128; i += 256) wl[i] = Wagg[i];
    for (int i = tid; i < 32 * 128; i += 256) {
        int row = i >> 7, j = i & 127;
        size_t rg = r0 + row;
        float s = aggbuf[rg * AGGD + j]
                + aggbuf[((size_t)MROWS + rg) * AGGD + j]
                + aggbuf[((size_t)2 * MROWS + rg) * AGGD + j];
        xl[i] = s * (1.0f / 3.0f);
    }
    __syncthreads();
    const int row = tid >> 3;
    const int jo0 = (tid & 7) * 16;
    float acc[16];
    #pragma unroll
    for (int jj = 0; jj < 16; ++jj) acc[jj] = 0.f;
    for (int j = 0; j < 128; ++j) {
        float xv = xl[row * 128 + j];
        const float* wr = &wl[j * 128 + jo0];
        #pragma unroll
        for (int jj = 0; jj < 16; ++jj) acc[jj] = fmaf(xv, wr[jj], acc[jj]);
    }
    size_t rg = r0 + row;
    #pragma unroll
    for (int jj = 0; jj < 16; ++jj) {
        float t = acc[jj] + bagg[jo0 + jj];
        float g = 0.5f * t * (1.0f + tanhf(0.7978845608028654f * (t + 0.044715f * t * t * t)));
        bf16 h = (bf16)g;
        size_t o = rg * 640 + 512 + jo0 + jj;
        xcat_hi[o] = h;
        xcat_lo[o] = (bf16)(g - (float)h);
    }
}

// ---- attention, NO-MAX softmax (scores bounded: |s*scale| <~ 2, exp-safe).
// pass1: QK^T + per-lane sum of exp (BK=128, no cross-lane work per tile).
// pass2: recompute S, P = exp(s)*invl, write attn fp32, PV. Counted vmcnt
// so the barrier never waits on the attn stores.
__global__ void __launch_bounds__(256) k_attn(const bf16* __restrict__ qsbuf, const bf16* __restrict__ vsT,
                                              float* __restrict__ gattn,
                                              bf16* __restrict__ xcat_hi, bf16* __restrict__ xcat_lo)
{
    __shared__ __align__(16) bf16 smem[2][8192];        // 32 KB (pass1: K128; pass2: K64+V64)
    __shared__ __align__(16) bf16 p_lds[4][16 * 64];    // 8 KB, per-wave private

    const int bh = blockIdx.y;
    const int b = bh >> 3, h = bh & 7;
    const int q0 = blockIdx.x * 64;
    const int tid = threadIdx.x, w = tid >> 6, lane = tid & 63;
    const int lr = lane & 15, lg = lane >> 4;

    const bf16* qbase = qsbuf + (size_t)(b * 8 + h) * (2048 * 64);          // p=0
    const bf16* kbase = qsbuf + (size_t)((2 + b) * 8 + h) * (2048 * 64);    // p=1
    const bf16* vtb   = vsT + (size_t)(b * 8 + h) * (64 * 2048);

    bf16x8 aq[2];
    {
        const bf16* qp = qbase + (size_t)(q0 + w * 16 + lr) * 64 + lg * 8;
        aq[0] = *(const bf16x8*)(qp);
        aq[1] = *(const bf16x8*)(qp + 32);
    }

    // ---- pass 1: row sums of exp(s*scale), BK=128
    float lsum[4] = {0.f, 0.f, 0.f, 0.f};
    stage_rows<1024>(smem[0], (const char*)kbase, 128, tid);
    int cur = 0;
    #pragma unroll 1
    for (int kt = 0; kt < 16; ++kt) {
        waitbar();
        if (kt < 15)
            stage_rows<1024>(smem[cur ^ 1], (const char*)kbase + (size_t)(kt + 1) * 16384, 128, tid);
        f32x4 s[8];
        {
            f32x4 z = {0.f, 0.f, 0.f, 0.f};
            #pragma unroll
            for (int ni = 0; ni < 8; ++ni) s[ni] = z;
        }
        #pragma unroll
        for (int ks = 0; ks < 2; ++ks)
            #pragma unroll
            for (int ni = 0; ni < 8; ++ni)
                s[ni] = mfma16(aq[ks], ldsfrag(smem[cur], ni * 16 + lr, ks * 64 + lg * 16), s[ni]);
        #pragma unroll
        for (int ni = 0; ni < 8; ++ni)
            #pragma unroll
            for (int r = 0; r < 4; ++r)
                lsum[r] += __expf(s[ni][r] * SCALE_QK);
        cur ^= 1;
    }
    float invl[4];
    #pragma unroll
    for (int r = 0; r < 4; ++r) {
        float t = lsum[r];
        t += __shfl_xor(t, 1);
        t += __shfl_xor(t, 2);
        t += __shfl_xor(t, 4);
        t += __shfl_xor(t, 8);
        invl[r] = 1.0f / t;
    }

    f32x4 o[4];
    {
        f32x4 z = {0.f, 0.f, 0.f, 0.f};
        #pragma unroll
        for (int ni = 0; ni < 4; ++ni) o[ni] = z;
    }
    float* attnrow = gattn + (size_t)bh * 2048 * 2048;

    // ---- pass 2 (BK=64): K in smem[cur][0..4095], V^T in smem[cur][4096..]
    stage_rows<512>(smem[0],        (const char*)kbase, 128, tid);
    stage_rows<512>(smem[0] + 4096, (const char*)vtb, 4096, tid);
    cur = 0;
    #pragma unroll 1
    for (int kt = 0; kt < 32; ++kt) {
        // drain only the 8 staging loads (stores are newer in the per-wave FIFO)
        if (kt == 0) asm volatile("s_waitcnt vmcnt(0)" ::: "memory");
        else         asm volatile("s_waitcnt vmcnt(16)" ::: "memory");
        __builtin_amdgcn_s_barrier();
        asm volatile("" ::: "memory");
        if (kt < 31) {
            stage_rows<512>(smem[cur ^ 1],        (const char*)kbase + (size_t)(kt + 1) * 8192, 128, tid);
            stage_rows<512>(smem[cur ^ 1] + 4096, (const char*)vtb + (size_t)(kt + 1) * 128, 4096, tid);
        }
        __builtin_amdgcn_sched_barrier(0);   // keep staging issue above the stores
        const bf16* kb = smem[cur];
        const bf16* vb = smem[cur] + 4096;
        f32x4 s[4];
        {
            f32x4 z = {0.f, 0.f, 0.f, 0.f};
            #pragma unroll
            for (int ni = 0; ni < 4; ++ni) s[ni] = z;
        }
        #pragma unroll
        for (int ks = 0; ks < 2; ++ks)
            #pragma unroll
            for (int ni = 0; ni < 4; ++ni)
                s[ni] = mfma16(aq[ks], ldsfrag(kb, ni * 16 + lr, ks * 64 + lg * 16), s[ni]);
        #pragma unroll
        for (int ni = 0; ni < 4; ++ni) {
            #pragma unroll
            for (int r = 0; r < 4; ++r) {
                float pv = __expf(s[ni][r] * SCALE_QK) * invl[r];
                int qr = q0 + w * 16 + lg * 4 + r;
                attnrow[(size_t)qr * 2048 + kt * 64 + ni * 16 + lr] = pv;
                int prow = lg * 4 + r;
                int pb = prow * 128 + (((ni * 16 + lr) * 2) ^ ((prow & 7) << 4));
                *(bf16*)((char*)&p_lds[w][0] + pb) = (bf16)pv;
            }
        }
        // p_lds[w] is wave-private: same-wave ds ordering via lgkmcnt only.
        #pragma unroll
        for (int ks = 0; ks < 2; ++ks) {
            bf16x8 pa = ldsfrag(&p_lds[w][0], lr, ks * 64 + lg * 16);
            #pragma unroll
            for (int ni = 0; ni < 4; ++ni)
                o[ni] = mfma16(pa, ldsfrag(vb, ni * 16 + lr, ks * 64 + lg * 16), o[ni]);
        }
        cur ^= 1;
    }

    #pragma unroll
    for (int ni = 0; ni < 4; ++ni) {
        #pragma unroll
        for (int r = 0; r < 4; ++r) {
            int qr = q0 + w * 16 + lg * 4 + r;
            size_t rg = (size_t)b * 2048 + qr;
            int c = h * 64 + ni * 16 + lr;
            float v = o[ni][r];
            bf16 hv = (bf16)v;
            xcat_hi[rg * 640 + c] = hv;
            xcat_lo[rg * 640 + c] = (bf16)(v - (float)hv);
        }
    }
}

// ---- out GEMM (BM=64 for occupancy: 320 blocks): d_out = xcat @ W_out + b_out
__global__ void __launch_bounds__(256) k_gemm_out(
    const bf16* __restrict__ Xhi, const bf16* __restrict__ Xlo,
    const bf16* __restrict__ BThi, const bf16* __restrict__ BTlo,
    const float* __restrict__ bout, float* __restrict__ out0)
{
    __shared__ __align__(16) bf16 lds[2 * (4096 + 8192)];   // 48 KB
    const int m0 = blockIdx.x * 64, n0 = blockIdx.y * 128;
    f32x4 acc[2][4];
    {
        f32x4 z = {0.f, 0.f, 0.f, 0.f};
        #pragma unroll
        for (int mi = 0; mi < 2; ++mi)
            #pragma unroll
            for (int ni = 0; ni < 4; ++ni) acc[mi][ni] = z;
    }
    gemm_main<2>(Xhi, Xlo, BThi, BTlo, m0, n0, lds, acc);

    const int tid = threadIdx.x, w = tid >> 6, lane = tid & 63;
    const int lr = lane & 15, lg = lane >> 4;
    const int wm = (w >> 1) * 32, wn = (w & 1) * 64;
    #pragma unroll
    for (int mi = 0; mi < 2; ++mi)
        #pragma unroll
        for (int ni = 0; ni < 4; ++ni) {
            int n = n0 + wn + ni * 16 + lr;
            float bv = bout[n];
            #pragma unroll
            for (int r = 0; r < 4; ++r) {
                int rg = m0 + wm + mi * 16 + lg * 4 + r;
                out0[(size_t)rg * 640 + n] = acc[mi][ni][r] + bv;
            }
        }
}

extern "C" void kernel_launch(void* const* d_in, const int* in_sizes, int n_in,
                              void* d_out, int out_size, void* d_ws, size_t ws_size,
                              hipStream_t stream)
{
    (void)in_sizes; (void)n_in; (void)out_size; (void)ws_size;
    const float* Q    = (const float*)d_in[0];
    const float* WQ   = (const float*)d_in[1];
    const float* bQ   = (const float*)d_in[2];
    const float* WK   = (const float*)d_in[3];
    const float* bK   = (const float*)d_in[4];
    const float* WV   = (const float*)d_in[5];
    const float* bV   = (const float*)d_in[6];
    const float* Wpos = (const float*)d_in[7];
    const float* Wagg = (const float*)d_in[8];
    const float* bagg = (const float*)d_in[9];
    const float* WO   = (const float*)d_in[10];
    const float* bout = (const float*)d_in[11];

    float* out0  = (float*)d_out;
    float* gattn = out0 + (size_t)MROWS * DIMN;   // attn output region (268 MB)

    char* ws = (char*)d_ws;
    bf16* Qhi      = (bf16*)(ws);                 ws += (size_t)MROWS * DIMN * 2;
    bf16* Qlo      = (bf16*)(ws);                 ws += (size_t)MROWS * DIMN * 2;
    bf16* BTqkv_hi = (bf16*)(ws);                 ws += (size_t)1920 * 640 * 2;
    bf16* BTqkv_lo = (bf16*)(ws);                 ws += (size_t)1920 * 640 * 2;
    bf16* BTout_hi = (bf16*)(ws);                 ws += (size_t)640 * 640 * 2;
    bf16* BTout_lo = (bf16*)(ws);                 ws += (size_t)640 * 640 * 2;
    bf16* qsbuf    = (bf16*)(ws);                 ws += (size_t)4 * 8 * 2048 * 64 * 2; // 8 MB
    bf16* vsT      = (bf16*)(ws);                 ws += (size_t)16 * 64 * 2048 * 2;    // 4 MB
    float* aggbuf  = (float*)(ws);                ws += (size_t)3 * MROWS * AGGD * 4;  // 6 MB
    bf16* xcat_hi  = (bf16*)(ws);                 ws += (size_t)MROWS * DIMN * 2;
    bf16* xcat_lo  = (bf16*)(ws);                 ws += (size_t)MROWS * DIMN * 2;

    k_split_q<<<dim3(2560), dim3(256), 0, stream>>>(Q, Qhi, Qlo);
    k_prep_w<<<dim3(100, 4), dim3(256), 0, stream>>>(WQ, WK, WV, WO,
                                                     BTqkv_hi, BTqkv_lo, BTout_hi, BTout_lo);
    k_gemm_qkv<<<dim3(32, 15), dim3(256), 0, stream>>>(Qhi, Qlo, BTqkv_hi, BTqkv_lo,
                                                       bQ, bK, bV, Wpos, qsbuf, vsT, aggbuf);
    k_agg<<<dim3(128), dim3(256), 0, stream>>>(aggbuf, Wagg, bagg, xcat_hi, xcat_lo);
    k_attn<<<dim3(32, 16), dim3(256), 0, stream>>>(qsbuf, vsT, gattn, xcat_hi, xcat_lo);
    k_gemm_out<<<dim3(64, 5), dim3(256), 0, stream>>>(xcat_hi, xcat_lo, BTout_hi, BTout_lo,
                                                      bout, out0);
}

// Round 5
// 168.026 us; speedup vs baseline: 1.4671x; 1.2239x over previous
//
#include <hip/hip_runtime.h>
#include <cstdint>
#include <cstddef>

// Problem constants
#define BSZ   2
#define QL    2048
#define DIMN  640
#define NH    8
#define CMAIN 512
#define AGGD  128
#define MROWS 4096                 // BSZ*QL
#define SCALE_QK 0.11180339887498948f   // (DIM/NHEADS)^-0.5 = 80^-0.5

typedef __bf16 bf16;
typedef __bf16 bf16x8 __attribute__((ext_vector_type(8)));
typedef __bf16 bf16x4v __attribute__((ext_vector_type(4)));
typedef float  f32x4  __attribute__((ext_vector_type(4)));

typedef __attribute__((address_space(1))) const uint32_t GU32;
typedef __attribute__((address_space(3))) uint32_t LU32;
#define GLL(g, l) __builtin_amdgcn_global_load_lds((GU32*)(g), (LU32*)(l), 16, 0, 0)

static __device__ __forceinline__ f32x4 mfma16(bf16x8 a, bf16x8 b, f32x4 c) {
    return __builtin_amdgcn_mfma_f32_16x16x32_bf16(a, b, c, 0, 0, 0);
}

static __device__ __forceinline__ void waitbar() {
    asm volatile("s_waitcnt vmcnt(0)" ::: "memory");
    __builtin_amdgcn_s_barrier();
    asm volatile("" ::: "memory");
}

// LDS tiles are [rows][64] bf16 (128 B/row), XOR-swizzled: byte ^= (row&7)<<4.
// global_load_lds writes LDS linearly, so the swizzle is applied by
// inverse-swizzling the per-lane GLOBAL source address (both-sides rule #21).
static __device__ __forceinline__ bf16x8 ldsfrag(const bf16* base, int row, int kbyte) {
    return *(const bf16x8*)((const char*)base + row * 128 + (kbyte ^ ((row & 7) << 4)));
}

// stage NCH 16B-chunks (= NCH/8 rows of 128B) from rows of `strideB` bytes.
// 256 threads. LDS dest is wave-uniform base; HW appends lane*16.
template<int NCH>
static __device__ __forceinline__ void stage_rows(bf16* ldsbuf, const char* gbase,
                                                  int strideB, int tid) {
    const int w = tid >> 6, lane = tid & 63;
    #pragma unroll
    for (int i = 0; i < NCH / 256; ++i) {
        int c = i * 256 + w * 64 + lane;
        int r = c >> 3;
        int kb = ((c & 7) * 16) ^ ((r & 7) << 4);     // inverse-swizzled byte-in-row
        GLL(gbase + (size_t)r * strideB + kb,
            (char*)ldsbuf + (size_t)(i * 256 + w * 64) * 16);
    }
}

// Plain-bf16 GEMM mainloop (fp32 MFMA accumulate). C = A*B; A [M][640] bf16,
// B^T [n][k=640] bf16. Block tile (MI*32)x128, 4 waves 2x2. Double-buffered,
// 1 barrier per 64-K chunk, 10 chunks.
template<int MI>
static __device__ __forceinline__ void gemm_main(
    const bf16* __restrict__ A, const bf16* __restrict__ BT,
    int m0, int n0, bf16* lds, f32x4 acc[MI][4])
{
    const int tid = threadIdx.x;
    const int w = tid >> 6, lane = tid & 63;
    const int lr = lane & 15, lg = lane >> 4;
    const int wm = (w >> 1) * (MI * 16), wn = (w & 1) * 64;
    constexpr int ASZ = MI * 2048;          // A-tile bf16 elems (MI*32 rows x 64)
    constexpr int BUF = ASZ + 8192;

    stage_rows<MI * 256>(lds,   (const char*)(A + (size_t)m0 * 640), 1280, tid);
    stage_rows<1024>(lds + ASZ, (const char*)(BT + (size_t)n0 * 640), 1280, tid);
    int cur = 0;
    #pragma unroll 1
    for (int ch = 0; ch < 10; ++ch) {
        waitbar();                                   // drain cur's loads; all waves synced
        if (ch < 9) {
            int kk = (ch + 1) * 64;
            bf16* nb = lds + (cur ^ 1) * BUF;
            stage_rows<MI * 256>(nb,   (const char*)(A + (size_t)m0 * 640 + kk), 1280, tid);
            stage_rows<1024>(nb + ASZ, (const char*)(BT + (size_t)n0 * 640 + kk), 1280, tid);
        }
        const bf16* cA = lds + cur * BUF;
        const bf16* cB = cA + ASZ;
        #pragma unroll
        for (int ks = 0; ks < 2; ++ks) {
            bf16x8 a[MI], b[4];
            #pragma unroll
            for (int i = 0; i < MI; ++i) a[i] = ldsfrag(cA, wm + i * 16 + lr, ks * 64 + lg * 16);
            #pragma unroll
            for (int i = 0; i < 4; ++i)  b[i] = ldsfrag(cB, wn + i * 16 + lr, ks * 64 + lg * 16);
            #pragma unroll
            for (int mi = 0; mi < MI; ++mi)
                #pragma unroll
                for (int ni = 0; ni < 4; ++ni)
                    acc[mi][ni] = mfma16(a[mi], b[ni], acc[mi][ni]);
        }
        cur ^= 1;
    }
}

// ---- prep: Q (4096x640 f32) -> bf16 ----
__global__ void __launch_bounds__(256) k_split_q(const float* __restrict__ Q,
                                                 bf16* __restrict__ Qbf) {
    int i = blockIdx.x * 256 + threadIdx.x;
    float4 v = ((const float4*)Q)[i];
    bf16x4v hv;
    hv[0] = (bf16)v.x; hv[1] = (bf16)v.y; hv[2] = (bf16)v.z; hv[3] = (bf16)v.w;
    *(bf16x4v*)(Qbf + (size_t)i * 4) = hv;
}

// ---- prep: coalesced LDS-transpose of W_Q/W_K/W_V/W_out into B^T bf16.
// grid (100, 4): 64x64 tile (tx=k-tile, ty=n-tile), y selects the matrix.
__global__ void __launch_bounds__(256) k_prep_w(
    const float* __restrict__ WQ, const float* __restrict__ WK,
    const float* __restrict__ WV, const float* __restrict__ WO,
    bf16* __restrict__ BTqkv, bf16* __restrict__ BTout)
{
    __shared__ float tl[64][65];     // tl[n_loc][k_loc]
    const int ty = blockIdx.x / 10, tx = blockIdx.x % 10;
    const int wsel = blockIdx.y;
    const float* W = (wsel == 0) ? WQ : (wsel == 1) ? WK : (wsel == 2) ? WV : WO;
    const int tid = threadIdx.x;
    const int rr = tid >> 4;             // k row group 0..15
    const int cc = (tid & 15) * 4;       // n col 0..60
    #pragma unroll
    for (int i = 0; i < 4; ++i) {
        int k = tx * 64 + rr + i * 16;
        float4 v = *(const float4*)(W + (size_t)k * 640 + ty * 64 + cc);
        tl[cc + 0][rr + i * 16] = v.x;
        tl[cc + 1][rr + i * 16] = v.y;
        tl[cc + 2][rr + i * 16] = v.z;
        tl[cc + 3][rr + i * 16] = v.w;
    }
    __syncthreads();
    bf16* dst; int nbase;
    if (wsel < 3) { dst = BTqkv; nbase = wsel * 640 + ty * 64; }
    else          { dst = BTout; nbase = ty * 64; }
    const int nl0 = tid >> 4;
    const int kl = (tid & 15) * 4;
    #pragma unroll
    for (int i = 0; i < 4; ++i) {
        int nl = nl0 + i * 16;
        bf16x4v hv;
        #pragma unroll
        for (int j = 0; j < 4; ++j) hv[j] = (bf16)tl[nl][kl + j];
        *(bf16x4v*)(dst + (size_t)(nbase + nl) * 640 + tx * 64 + kl) = hv;
    }
}

// ---- QKV GEMM: C[4096][1920] ; epilogue adds bias (+W_pos) and routes outputs
__global__ void __launch_bounds__(256) k_gemm_qkv(
    const bf16* __restrict__ Qbf, const bf16* __restrict__ BT,
    const float* __restrict__ bQ, const float* __restrict__ bK, const float* __restrict__ bV,
    const float* __restrict__ Wpos,
    bf16* __restrict__ qsbuf, bf16* __restrict__ vsT, float* __restrict__ aggbuf)
{
    __shared__ __align__(16) bf16 lds[2 * (8192 + 8192)];   // 64 KB
    const int m0 = blockIdx.x * 128, n0 = blockIdx.y * 128;
    f32x4 acc[4][4];
    {
        f32x4 z = {0.f, 0.f, 0.f, 0.f};
        #pragma unroll
        for (int mi = 0; mi < 4; ++mi)
            #pragma unroll
            for (int ni = 0; ni < 4; ++ni) acc[mi][ni] = z;
    }
    gemm_main<4>(Qbf, BT, m0, n0, lds, acc);

    const int tid = threadIdx.x, w = tid >> 6, lane = tid & 63;
    const int lr = lane & 15, lg = lane >> 4;
    const int wm = (w >> 1) * 64, wn = (w & 1) * 64;
    const int p = n0 / 640;                       // block-uniform (640 % 128 == 0)
    const float* bias = (p == 0) ? bQ : (p == 1) ? bK : bV;

    #pragma unroll
    for (int mi = 0; mi < 4; ++mi)
        #pragma unroll
        for (int ni = 0; ni < 4; ++ni) {
            int n = n0 + wn + ni * 16 + lr;
            int c = n - p * 640;
            int rbase = m0 + wm + mi * 16 + lg * 4;
            float bval = bias[c];
            if (c < 512) {
                int hh = c >> 6, d = c & 63;
                #pragma unroll
                for (int r = 0; r < 4; ++r) {
                    int rg = rbase + r;
                    int bb = rg >> 11, l = rg & 2047;
                    float v = acc[mi][ni][r] + bval + Wpos[(size_t)l * 512 + c];
                    if (p < 2)
                        qsbuf[(((size_t)(p * 2 + bb) * 8 + hh) * 2048 + l) * 64 + d] = (bf16)v;
                    else
                        vsT[(((size_t)(bb * 8 + hh)) * 64 + d) * 2048 + l] = (bf16)v;
                }
            } else {
                int j = c - 512;
                #pragma unroll
                for (int r = 0; r < 4; ++r) {
                    int rg = rbase + r;
                    aggbuf[((size_t)p * MROWS + rg) * AGGD + j] = acc[mi][ni][r] + bval;
                }
            }
        }
}

// ---- agg: x = mean3(aggbuf) ; gelu_tanh(x @ W_agg + b_agg) -> xcat cols 512..639
__global__ void __launch_bounds__(256) k_agg(const float* __restrict__ aggbuf,
                                             const float* __restrict__ Wagg, const float* __restrict__ bagg,
                                             bf16* __restrict__ xcat)
{
    __shared__ float wl[128 * 128];
    __shared__ float xl[32 * 128];
    const int tid = threadIdx.x;
    const int r0 = blockIdx.x * 32;
    for (int i = tid; i < 128 * 128; i += 256) wl[i] = Wagg[i];
    for (int i = tid; i < 32 * 128; i += 256) {
        int row = i >> 7, j = i & 127;
        size_t rg = r0 + row;
        float s = aggbuf[rg * AGGD + j]
                + aggbuf[((size_t)MROWS + rg) * AGGD + j]
                + aggbuf[((size_t)2 * MROWS + rg) * AGGD + j];
        xl[i] = s * (1.0f / 3.0f);
    }
    __syncthreads();
    const int row = tid >> 3;
    const int jo0 = (tid & 7) * 16;
    float acc[16];
    #pragma unroll
    for (int jj = 0; jj < 16; ++jj) acc[jj] = 0.f;
    for (int j = 0; j < 128; ++j) {
        float xv = xl[row * 128 + j];
        const float* wr = &wl[j * 128 + jo0];
        #pragma unroll
        for (int jj = 0; jj < 16; ++jj) acc[jj] = fmaf(xv, wr[jj], acc[jj]);
    }
    size_t rg = r0 + row;
    #pragma unroll
    for (int jj = 0; jj < 16; ++jj) {
        float t = acc[jj] + bagg[jo0 + jj];
        float g = 0.5f * t * (1.0f + tanhf(0.7978845608028654f * (t + 0.044715f * t * t * t)));
        xcat[rg * 640 + 512 + jo0 + jj] = (bf16)g;
    }
}

// ---- attention, NO-MAX softmax (scores bounded: |s*scale| <~ 2, exp-safe).
// pass1: QK^T + per-lane sum of exp (BK=128). pass2: recompute S,
// P = exp(s)*invl, write attn fp32, PV. Counted vmcnt so the barrier never
// waits on the attn stores.
__global__ void __launch_bounds__(256) k_attn(const bf16* __restrict__ qsbuf, const bf16* __restrict__ vsT,
                                              float* __restrict__ gattn,
                                              bf16* __restrict__ xcat)
{
    __shared__ __align__(16) bf16 smem[2][8192];        // 32 KB (pass1: K128; pass2: K64+V64)
    __shared__ __align__(16) bf16 p_lds[4][16 * 64];    // 8 KB, per-wave private

    const int bh = blockIdx.y;
    const int b = bh >> 3, h = bh & 7;
    const int q0 = blockIdx.x * 64;
    const int tid = threadIdx.x, w = tid >> 6, lane = tid & 63;
    const int lr = lane & 15, lg = lane >> 4;

    const bf16* qbase = qsbuf + (size_t)(b * 8 + h) * (2048 * 64);          // p=0
    const bf16* kbase = qsbuf + (size_t)((2 + b) * 8 + h) * (2048 * 64);    // p=1
    const bf16* vtb   = vsT + (size_t)(b * 8 + h) * (64 * 2048);

    bf16x8 aq[2];
    {
        const bf16* qp = qbase + (size_t)(q0 + w * 16 + lr) * 64 + lg * 8;
        aq[0] = *(const bf16x8*)(qp);
        aq[1] = *(const bf16x8*)(qp + 32);
    }

    // ---- pass 1: row sums of exp(s*scale), BK=128
    float lsum[4] = {0.f, 0.f, 0.f, 0.f};
    stage_rows<1024>(smem[0], (const char*)kbase, 128, tid);
    int cur = 0;
    #pragma unroll 1
    for (int kt = 0; kt < 16; ++kt) {
        waitbar();
        if (kt < 15)
            stage_rows<1024>(smem[cur ^ 1], (const char*)kbase + (size_t)(kt + 1) * 16384, 128, tid);
        f32x4 s[8];
        {
            f32x4 z = {0.f, 0.f, 0.f, 0.f};
            #pragma unroll
            for (int ni = 0; ni < 8; ++ni) s[ni] = z;
        }
        #pragma unroll
        for (int ks = 0; ks < 2; ++ks)
            #pragma unroll
            for (int ni = 0; ni < 8; ++ni)
                s[ni] = mfma16(aq[ks], ldsfrag(smem[cur], ni * 16 + lr, ks * 64 + lg * 16), s[ni]);
        #pragma unroll
        for (int ni = 0; ni < 8; ++ni)
            #pragma unroll
            for (int r = 0; r < 4; ++r)
                lsum[r] += __expf(s[ni][r] * SCALE_QK);
        cur ^= 1;
    }
    float invl[4];
    #pragma unroll
    for (int r = 0; r < 4; ++r) {
        float t = lsum[r];
        t += __shfl_xor(t, 1);
        t += __shfl_xor(t, 2);
        t += __shfl_xor(t, 4);
        t += __shfl_xor(t, 8);
        invl[r] = 1.0f / t;
    }

    f32x4 o[4];
    {
        f32x4 z = {0.f, 0.f, 0.f, 0.f};
        #pragma unroll
        for (int ni = 0; ni < 4; ++ni) o[ni] = z;
    }
    float* attnrow = gattn + (size_t)bh * 2048 * 2048;

    // ---- pass 2 (BK=64): K in smem[cur][0..4095], V^T in smem[cur][4096..]
    stage_rows<512>(smem[0],        (const char*)kbase, 128, tid);
    stage_rows<512>(smem[0] + 4096, (const char*)vtb, 4096, tid);
    cur = 0;
    #pragma unroll 1
    for (int kt = 0; kt < 32; ++kt) {
        // drain only the 8 staging loads (stores are newer in the per-wave FIFO)
        if (kt == 0) asm volatile("s_waitcnt vmcnt(0)" ::: "memory");
        else         asm volatile("s_waitcnt vmcnt(16)" ::: "memory");
        __builtin_amdgcn_s_barrier();
        asm volatile("" ::: "memory");
        if (kt < 31) {
            stage_rows<512>(smem[cur ^ 1],        (const char*)kbase + (size_t)(kt + 1) * 8192, 128, tid);
            stage_rows<512>(smem[cur ^ 1] + 4096, (const char*)vtb + (size_t)(kt + 1) * 128, 4096, tid);
        }
        __builtin_amdgcn_sched_barrier(0);   // keep staging issue above the stores
        const bf16* kb = smem[cur];
        const bf16* vb = smem[cur] + 4096;
        f32x4 s[4];
        {
            f32x4 z = {0.f, 0.f, 0.f, 0.f};
            #pragma unroll
            for (int ni = 0; ni < 4; ++ni) s[ni] = z;
        }
        #pragma unroll
        for (int ks = 0; ks < 2; ++ks)
            #pragma unroll
            for (int ni = 0; ni < 4; ++ni)
                s[ni] = mfma16(aq[ks], ldsfrag(kb, ni * 16 + lr, ks * 64 + lg * 16), s[ni]);
        #pragma unroll
        for (int ni = 0; ni < 4; ++ni) {
            #pragma unroll
            for (int r = 0; r < 4; ++r) {
                float pv = __expf(s[ni][r] * SCALE_QK) * invl[r];
                int qr = q0 + w * 16 + lg * 4 + r;
                attnrow[(size_t)qr * 2048 + kt * 64 + ni * 16 + lr] = pv;
                int prow = lg * 4 + r;
                int pb = prow * 128 + (((ni * 16 + lr) * 2) ^ ((prow & 7) << 4));
                *(bf16*)((char*)&p_lds[w][0] + pb) = (bf16)pv;
            }
        }
        // p_lds[w] is wave-private: same-wave ds ordering via lgkmcnt only.
        #pragma unroll
        for (int ks = 0; ks < 2; ++ks) {
            bf16x8 pa = ldsfrag(&p_lds[w][0], lr, ks * 64 + lg * 16);
            #pragma unroll
            for (int ni = 0; ni < 4; ++ni)
                o[ni] = mfma16(pa, ldsfrag(vb, ni * 16 + lr, ks * 64 + lg * 16), o[ni]);
        }
        cur ^= 1;
    }

    #pragma unroll
    for (int ni = 0; ni < 4; ++ni) {
        #pragma unroll
        for (int r = 0; r < 4; ++r) {
            int qr = q0 + w * 16 + lg * 4 + r;
            size_t rg = (size_t)b * 2048 + qr;
            int c = h * 64 + ni * 16 + lr;
            xcat[rg * 640 + c] = (bf16)o[ni][r];
        }
    }
}

// ---- out GEMM (BM=64 for occupancy: 320 blocks): d_out = xcat @ W_out + b_out
__global__ void __launch_bounds__(256) k_gemm_out(
    const bf16* __restrict__ X, const bf16* __restrict__ BT,
    const float* __restrict__ bout, float* __restrict__ out0)
{
    __shared__ __align__(16) bf16 lds[2 * (4096 + 8192)];   // 48 KB
    const int m0 = blockIdx.x * 64, n0 = blockIdx.y * 128;
    f32x4 acc[2][4];
    {
        f32x4 z = {0.f, 0.f, 0.f, 0.f};
        #pragma unroll
        for (int mi = 0; mi < 2; ++mi)
            #pragma unroll
            for (int ni = 0; ni < 4; ++ni) acc[mi][ni] = z;
    }
    gemm_main<2>(X, BT, m0, n0, lds, acc);

    const int tid = threadIdx.x, w = tid >> 6, lane = tid & 63;
    const int lr = lane & 15, lg = lane >> 4;
    const int wm = (w >> 1) * 32, wn = (w & 1) * 64;
    #pragma unroll
    for (int mi = 0; mi < 2; ++mi)
        #pragma unroll
        for (int ni = 0; ni < 4; ++ni) {
            int n = n0 + wn + ni * 16 + lr;
            float bv = bout[n];
            #pragma unroll
            for (int r = 0; r < 4; ++r) {
                int rg = m0 + wm + mi * 16 + lg * 4 + r;
                out0[(size_t)rg * 640 + n] = acc[mi][ni][r] + bv;
            }
        }
}

extern "C" void kernel_launch(void* const* d_in, const int* in_sizes, int n_in,
                              void* d_out, int out_size, void* d_ws, size_t ws_size,
                              hipStream_t stream)
{
    (void)in_sizes; (void)n_in; (void)out_size; (void)ws_size;
    const float* Q    = (const float*)d_in[0];
    const float* WQ   = (const float*)d_in[1];
    const float* bQ   = (const float*)d_in[2];
    const float* WK   = (const float*)d_in[3];
    const float* bK   = (const float*)d_in[4];
    const float* WV   = (const float*)d_in[5];
    const float* bV   = (const float*)d_in[6];
    const float* Wpos = (const float*)d_in[7];
    const float* Wagg = (const float*)d_in[8];
    const float* bagg = (const float*)d_in[9];
    const float* WO   = (const float*)d_in[10];
    const float* bout = (const float*)d_in[11];

    float* out0  = (float*)d_out;
    float* gattn = out0 + (size_t)MROWS * DIMN;   // attn output region (268 MB)

    char* ws = (char*)d_ws;
    bf16* Qbf    = (bf16*)(ws);                 ws += (size_t)MROWS * DIMN * 2;      // 5.24 MB
    bf16* BTqkv  = (bf16*)(ws);                 ws += (size_t)1920 * 640 * 2;        // 2.46 MB
    bf16* BTout  = (bf16*)(ws);                 ws += (size_t)640 * 640 * 2;         // 0.82 MB
    bf16* qsbuf  = (bf16*)(ws);                 ws += (size_t)4 * 8 * 2048 * 64 * 2; // 8 MB (q+k)
    bf16* vsT    = (bf16*)(ws);                 ws += (size_t)16 * 64 * 2048 * 2;    // 4 MB
    float* aggbuf= (float*)(ws);                ws += (size_t)3 * MROWS * AGGD * 4;  // 6 MB
    bf16* xcat   = (bf16*)(ws);                 ws += (size_t)MROWS * DIMN * 2;      // 5.24 MB

    k_split_q<<<dim3(2560), dim3(256), 0, stream>>>(Q, Qbf);
    k_prep_w<<<dim3(100, 4), dim3(256), 0, stream>>>(WQ, WK, WV, WO, BTqkv, BTout);
    k_gemm_qkv<<<dim3(32, 15), dim3(256), 0, stream>>>(Qbf, BTqkv,
                                                       bQ, bK, bV, Wpos, qsbuf, vsT, aggbuf);
    k_agg<<<dim3(128), dim3(256), 0, stream>>>(aggbuf, Wagg, bagg, xcat);
    k_attn<<<dim3(32, 16), dim3(256), 0, stream>>>(qsbuf, vsT, gattn, xcat);
    k_gemm_out<<<dim3(64, 5), dim3(256), 0, stream>>>(xcat, BTout, bout, out0);
}

// Round 7
// 156.504 us; speedup vs baseline: 1.5751x; 1.0736x over previous
//
#include <hip/hip_runtime.h>
#include <cstdint>
#include <cstddef>

// Problem constants
#define BSZ   2
#define QL    2048
#define DIMN  640
#define NH    8
#define CMAIN 512
#define AGGD  128
#define MROWS 4096                 // BSZ*QL
#define SCALE_QK 0.11180339887498948f   // (DIM/NHEADS)^-0.5 = 80^-0.5
#define C2EXP (SCALE_QK * 1.4426950408889634f)   // scale * log2(e)

typedef __bf16 bf16;
typedef __bf16 bf16x8 __attribute__((ext_vector_type(8)));
typedef __bf16 bf16x4v __attribute__((ext_vector_type(4)));
typedef float  f32x4  __attribute__((ext_vector_type(4)));

typedef __attribute__((address_space(1))) const uint32_t GU32;
typedef __attribute__((address_space(3))) uint32_t LU32;
#define GLL(g, l) __builtin_amdgcn_global_load_lds((GU32*)(g), (LU32*)(l), 16, 0, 0)

// hardware transcendentals (base-2): v_exp_f32 / v_log_f32
#define EXP2F(x) __builtin_amdgcn_exp2f(x)
#define LOG2F(x) __builtin_amdgcn_logf(x)

static __device__ __forceinline__ f32x4 mfma16(bf16x8 a, bf16x8 b, f32x4 c) {
    return __builtin_amdgcn_mfma_f32_16x16x32_bf16(a, b, c, 0, 0, 0);
}

static __device__ __forceinline__ void waitbar() {
    asm volatile("s_waitcnt vmcnt(0)" ::: "memory");
    __builtin_amdgcn_s_barrier();
    asm volatile("" ::: "memory");
}

// LDS tiles: rows of ROWB bytes, XOR-swizzled byte ^= (row&7)<<4.
// global_load_lds writes LDS linearly, so the swizzle is applied by
// inverse-swizzling the per-lane GLOBAL source address (both-sides rule #21).
template<int ROWB>
static __device__ __forceinline__ bf16x8 ldsfragR(const bf16* base, int row, int kbyte) {
    return *(const bf16x8*)((const char*)base + row * ROWB + (kbyte ^ ((row & 7) << 4)));
}

// stage NCH 16B-chunks into LDS rows of ROWB bytes from global rows of strideB.
template<int NCH, int ROWB>
static __device__ __forceinline__ void stage_rowsR(bf16* ldsbuf, const char* gbase,
                                                   int strideB, int tid) {
    const int w = tid >> 6, lane = tid & 63;
    #pragma unroll
    for (int i = 0; i < NCH / 256; ++i) {
        int c = i * 256 + w * 64 + lane;
        int r = c / (ROWB / 16);
        int kb = ((c % (ROWB / 16)) * 16) ^ ((r & 7) << 4);   // inverse-swizzled
        GLL(gbase + (size_t)r * strideB + kb,
            (char*)ldsbuf + (size_t)(i * 256 + w * 64) * 16);
    }
}

// Plain-bf16 GEMM mainloop (fp32 MFMA accumulate). C = A*B; A [M][640] bf16,
// B^T [n][k=640] bf16. Block tile (MI*32)x128, 4 waves 2x2. Double-buffered,
// 1 barrier per 64-K chunk, 10 chunks.
template<int MI>
static __device__ __forceinline__ void gemm_main(
    const bf16* __restrict__ A, const bf16* __restrict__ BT,
    int m0, int n0, bf16* lds, f32x4 acc[MI][4])
{
    const int tid = threadIdx.x;
    const int w = tid >> 6, lane = tid & 63;
    const int lr = lane & 15, lg = lane >> 4;
    const int wm = (w >> 1) * (MI * 16), wn = (w & 1) * 64;
    constexpr int ASZ = MI * 2048;          // A-tile bf16 elems (MI*32 rows x 64)
    constexpr int BUF = ASZ + 8192;

    stage_rowsR<MI * 256, 128>(lds,   (const char*)(A + (size_t)m0 * 640), 1280, tid);
    stage_rowsR<1024, 128>(lds + ASZ, (const char*)(BT + (size_t)n0 * 640), 1280, tid);
    int cur = 0;
    #pragma unroll 1
    for (int ch = 0; ch < 10; ++ch) {
        waitbar();                                   // drain cur's loads; all waves synced
        if (ch < 9) {
            int kk = (ch + 1) * 64;
            bf16* nb = lds + (cur ^ 1) * BUF;
            stage_rowsR<MI * 256, 128>(nb,   (const char*)(A + (size_t)m0 * 640 + kk), 1280, tid);
            stage_rowsR<1024, 128>(nb + ASZ, (const char*)(BT + (size_t)n0 * 640 + kk), 1280, tid);
        }
        const bf16* cA = lds + cur * BUF;
        const bf16* cB = cA + ASZ;
        #pragma unroll
        for (int ks = 0; ks < 2; ++ks) {
            bf16x8 a[MI], b[4];
            #pragma unroll
            for (int i = 0; i < MI; ++i) a[i] = ldsfragR<128>(cA, wm + i * 16 + lr, ks * 64 + lg * 16);
            #pragma unroll
            for (int i = 0; i < 4; ++i)  b[i] = ldsfragR<128>(cB, wn + i * 16 + lr, ks * 64 + lg * 16);
            #pragma unroll
            for (int mi = 0; mi < MI; ++mi)
                #pragma unroll
                for (int ni = 0; ni < 4; ++ni)
                    acc[mi][ni] = mfma16(a[mi], b[ni], acc[mi][ni]);
        }
        cur ^= 1;
    }
}

// ---- prep: Q (4096x640 f32) -> bf16 ----
__global__ void __launch_bounds__(256) k_split_q(const float* __restrict__ Q,
                                                 bf16* __restrict__ Qbf) {
    int i = blockIdx.x * 256 + threadIdx.x;
    float4 v = ((const float4*)Q)[i];
    bf16x4v hv;
    hv[0] = (bf16)v.x; hv[1] = (bf16)v.y; hv[2] = (bf16)v.z; hv[3] = (bf16)v.w;
    *(bf16x4v*)(Qbf + (size_t)i * 4) = hv;
}

// ---- prep: coalesced LDS-transpose of W_Q/W_K/W_V/W_out into B^T bf16.
__global__ void __launch_bounds__(256) k_prep_w(
    const float* __restrict__ WQ, const float* __restrict__ WK,
    const float* __restrict__ WV, const float* __restrict__ WO,
    bf16* __restrict__ BTqkv, bf16* __restrict__ BTout)
{
    __shared__ float tl[64][65];     // tl[n_loc][k_loc]
    const int ty = blockIdx.x / 10, tx = blockIdx.x % 10;
    const int wsel = blockIdx.y;
    const float* W = (wsel == 0) ? WQ : (wsel == 1) ? WK : (wsel == 2) ? WV : WO;
    const int tid = threadIdx.x;
    const int rr = tid >> 4;             // k row group 0..15
    const int cc = (tid & 15) * 4;       // n col 0..60
    #pragma unroll
    for (int i = 0; i < 4; ++i) {
        int k = tx * 64 + rr + i * 16;
        float4 v = *(const float4*)(W + (size_t)k * 640 + ty * 64 + cc);
        tl[cc + 0][rr + i * 16] = v.x;
        tl[cc + 1][rr + i * 16] = v.y;
        tl[cc + 2][rr + i * 16] = v.z;
        tl[cc + 3][rr + i * 16] = v.w;
    }
    __syncthreads();
    bf16* dst; int nbase;
    if (wsel < 3) { dst = BTqkv; nbase = wsel * 640 + ty * 64; }
    else          { dst = BTout; nbase = ty * 64; }
    const int nl0 = tid >> 4;
    const int kl = (tid & 15) * 4;
    #pragma unroll
    for (int i = 0; i < 4; ++i) {
        int nl = nl0 + i * 16;
        bf16x4v hv;
        #pragma unroll
        for (int j = 0; j < 4; ++j) hv[j] = (bf16)tl[nl][kl + j];
        *(bf16x4v*)(dst + (size_t)(nbase + nl) * 640 + tx * 64 + kl) = hv;
    }
}

// ---- QKV GEMM: C[4096][1920] ; epilogue adds bias (+W_pos) and routes outputs
__global__ void __launch_bounds__(256) k_gemm_qkv(
    const bf16* __restrict__ Qbf, const bf16* __restrict__ BT,
    const float* __restrict__ bQ, const float* __restrict__ bK, const float* __restrict__ bV,
    const float* __restrict__ Wpos,
    bf16* __restrict__ qsbuf, bf16* __restrict__ vsT, float* __restrict__ aggbuf)
{
    __shared__ __align__(16) bf16 lds[2 * (8192 + 8192)];   // 64 KB
    const int m0 = blockIdx.x * 128, n0 = blockIdx.y * 128;
    f32x4 acc[4][4];
    {
        f32x4 z = {0.f, 0.f, 0.f, 0.f};
        #pragma unroll
        for (int mi = 0; mi < 4; ++mi)
            #pragma unroll
            for (int ni = 0; ni < 4; ++ni) acc[mi][ni] = z;
    }
    gemm_main<4>(Qbf, BT, m0, n0, lds, acc);

    const int tid = threadIdx.x, w = tid >> 6, lane = tid & 63;
    const int lr = lane & 15, lg = lane >> 4;
    const int wm = (w >> 1) * 64, wn = (w & 1) * 64;
    const int p = n0 / 640;                       // block-uniform (640 % 128 == 0)
    const float* bias = (p == 0) ? bQ : (p == 1) ? bK : bV;

    #pragma unroll
    for (int mi = 0; mi < 4; ++mi)
        #pragma unroll
        for (int ni = 0; ni < 4; ++ni) {
            int n = n0 + wn + ni * 16 + lr;
            int c = n - p * 640;
            int rbase = m0 + wm + mi * 16 + lg * 4;
            float bval = bias[c];
            if (c < 512) {
                int hh = c >> 6, d = c & 63;
                #pragma unroll
                for (int r = 0; r < 4; ++r) {
                    int rg = rbase + r;
                    int bb = rg >> 11, l = rg & 2047;
                    float v = acc[mi][ni][r] + bval + Wpos[(size_t)l * 512 + c];
                    if (p < 2)
                        qsbuf[(((size_t)(p * 2 + bb) * 8 + hh) * 2048 + l) * 64 + d] = (bf16)v;
                    else
                        vsT[(((size_t)(bb * 8 + hh)) * 64 + d) * 2048 + l] = (bf16)v;
                }
            } else {
                int j = c - 512;
                #pragma unroll
                for (int r = 0; r < 4; ++r) {
                    int rg = rbase + r;
                    aggbuf[((size_t)p * MROWS + rg) * AGGD + j] = acc[mi][ni][r] + bval;
                }
            }
        }
}

// ---- agg: x = mean3(aggbuf) ; gelu_tanh(x @ W_agg + b_agg) -> xcat cols 512..639
__global__ void __launch_bounds__(256) k_agg(const float* __restrict__ aggbuf,
                                             const float* __restrict__ Wagg, const float* __restrict__ bagg,
                                             bf16* __restrict__ xcat)
{
    __shared__ float wl[128 * 128];
    __shared__ float xl[32 * 128];
    const int tid = threadIdx.x;
    const int r0 = blockIdx.x * 32;
    for (int i = tid; i < 128 * 128; i += 256) wl[i] = Wagg[i];
    for (int i = tid; i < 32 * 128; i += 256) {
        int row = i >> 7, j = i & 127;
        size_t rg = r0 + row;
        float s = aggbuf[rg * AGGD + j]
                + aggbuf[((size_t)MROWS + rg) * AGGD + j]
                + aggbuf[((size_t)2 * MROWS + rg) * AGGD + j];
        xl[i] = s * (1.0f / 3.0f);
    }
    __syncthreads();
    const int row = tid >> 3;
    const int jo0 = (tid & 7) * 16;
    float acc[16];
    #pragma unroll
    for (int jj = 0; jj < 16; ++jj) acc[jj] = 0.f;
    for (int j = 0; j < 128; ++j) {
        float xv = xl[row * 128 + j];
        const float* wr = &wl[j * 128 + jo0];
        #pragma unroll
        for (int jj = 0; jj < 16; ++jj) acc[jj] = fmaf(xv, wr[jj], acc[jj]);
    }
    size_t rg = r0 + row;
    #pragma unroll
    for (int jj = 0; jj < 16; ++jj) {
        float t = acc[jj] + bagg[jo0 + jj];
        float g = 0.5f * t * (1.0f + tanhf(0.7978845608028654f * (t + 0.044715f * t * t * t)));
        xcat[rg * 640 + 512 + jo0 + jj] = (bf16)g;
    }
}

// ---- attention, NO-MAX softmax, SWAPPED QK^T (T12): s = mfma(K_frag, Q_frag)
// gives lane-local P rows: lane holds P[q=lr][k=ni*16+lg*4+r].
// pass1: BK=128, per-lane exp2 sums, reduce via shfl_xor(16/32).
// pass2: BK=128, p = exp2(fma(s,C2,l2i)) (normalization folded into exponent),
// float4 attn stores, packed b64 p_lds writes, counted vmcnt(8).
__global__ void __launch_bounds__(256) k_attn(const bf16* __restrict__ qsbuf, const bf16* __restrict__ vsT,
                                              float* __restrict__ gattn,
                                              bf16* __restrict__ xcat)
{
    __shared__ __align__(16) bf16 smem[2][16384];       // 64 KB: K[128][128B] + V[64][256B]
    __shared__ __align__(16) bf16 p_lds[4][16 * 128];   // 16 KB, per-wave [16 q][256B]

    const int bh = blockIdx.y;
    const int b = bh >> 3, h = bh & 7;
    const int q0 = blockIdx.x * 64;
    const int tid = threadIdx.x, w = tid >> 6, lane = tid & 63;
    const int lr = lane & 15, lg = lane >> 4;

    const bf16* qbase = qsbuf + (size_t)(b * 8 + h) * (2048 * 64);          // p=0
    const bf16* kbase = qsbuf + (size_t)((2 + b) * 8 + h) * (2048 * 64);    // p=1
    const bf16* vtb   = vsT + (size_t)(b * 8 + h) * (64 * 2048);

    bf16x8 aq[2];
    {
        const bf16* qp = qbase + (size_t)(q0 + w * 16 + lr) * 64 + lg * 8;
        aq[0] = *(const bf16x8*)(qp);
        aq[1] = *(const bf16x8*)(qp + 32);
    }

    // ---- pass 1: denominator sums, BK=128
    float lsum = 0.f;
    stage_rowsR<1024, 128>(smem[0], (const char*)kbase, 128, tid);
    int cur = 0;
    #pragma unroll 1
    for (int kt = 0; kt < 16; ++kt) {
        waitbar();
        if (kt < 15)
            stage_rowsR<1024, 128>(smem[cur ^ 1], (const char*)kbase + (size_t)(kt + 1) * 16384, 128, tid);
        __builtin_amdgcn_sched_barrier(0);
        const bf16* kb = smem[cur];
        f32x4 s[8];
        {
            f32x4 z = {0.f, 0.f, 0.f, 0.f};
            #pragma unroll
            for (int ni = 0; ni < 8; ++ni) s[ni] = z;
        }
        #pragma unroll
        for (int ks = 0; ks < 2; ++ks)
            #pragma unroll
            for (int ni = 0; ni < 8; ++ni)
                s[ni] = mfma16(ldsfragR<128>(kb, ni * 16 + lr, ks * 64 + lg * 16), aq[ks], s[ni]);
        #pragma unroll
        for (int ni = 0; ni < 8; ++ni)
            #pragma unroll
            for (int r = 0; r < 4; ++r)
                lsum += EXP2F(s[ni][r] * C2EXP);
        cur ^= 1;
    }
    lsum += __shfl_xor(lsum, 16);
    lsum += __shfl_xor(lsum, 32);
    const float l2i = -LOG2F(lsum);

    f32x4 o[4];
    {
        f32x4 z = {0.f, 0.f, 0.f, 0.f};
        #pragma unroll
        for (int ni = 0; ni < 4; ++ni) o[ni] = z;
    }
    float* attnrow = gattn + (size_t)bh * 2048 * 2048 + (size_t)(q0 + w * 16 + lr) * 2048;

    // ---- pass 2: BK=128; K in smem[cur][0..8191], V^T in smem[cur][8192..]
    stage_rowsR<1024, 128>(smem[0],        (const char*)kbase, 128, tid);
    stage_rowsR<1024, 256>(smem[0] + 8192, (const char*)vtb, 4096, tid);
    cur = 0;
    #pragma unroll 1
    for (int kt = 0; kt < 16; ++kt) {
        // drain the 8 staging loads; stores (8/lane, newer in FIFO) may remain
        if (kt == 0) asm volatile("s_waitcnt vmcnt(0)" ::: "memory");
        else         asm volatile("s_waitcnt vmcnt(8)" ::: "memory");
        __builtin_amdgcn_s_barrier();
        asm volatile("" ::: "memory");
        if (kt < 15) {
            stage_rowsR<1024, 128>(smem[cur ^ 1],        (const char*)kbase + (size_t)(kt + 1) * 16384, 128, tid);
            stage_rowsR<1024, 256>(smem[cur ^ 1] + 8192, (const char*)vtb + (size_t)(kt + 1) * 256, 4096, tid);
        }
        __builtin_amdgcn_sched_barrier(0);   // keep staging issue ahead of compute/stores
        const bf16* kb = smem[cur];
        const bf16* vb = smem[cur] + 8192;
        f32x4 s[8];
        {
            f32x4 z = {0.f, 0.f, 0.f, 0.f};
            #pragma unroll
            for (int ni = 0; ni < 8; ++ni) s[ni] = z;
        }
        #pragma unroll
        for (int ks = 0; ks < 2; ++ks)
            #pragma unroll
            for (int ni = 0; ni < 8; ++ni)
                s[ni] = mfma16(ldsfragR<128>(kb, ni * 16 + lr, ks * 64 + lg * 16), aq[ks], s[ni]);
        bf16* pl = &p_lds[w][0];
        float* arow = attnrow + kt * 128;
        #pragma unroll
        for (int ni = 0; ni < 8; ++ni) {
            f32x4 p;
            #pragma unroll
            for (int r = 0; r < 4; ++r) p[r] = EXP2F(fmaf(s[ni][r], C2EXP, l2i));
            *(f32x4*)(arow + ni * 16 + lg * 4) = p;          // dwordx4 attn store
            bf16x4v pb;
            #pragma unroll
            for (int r = 0; r < 4; ++r) pb[r] = (bf16)p[r];
            *(bf16x4v*)((char*)pl + lr * 256 + ((ni * 32 + lg * 8) ^ ((lr & 7) << 4))) = pb;
        }
        #pragma unroll
        for (int ks = 0; ks < 4; ++ks) {
            bf16x8 pa = ldsfragR<256>(pl, lr, ks * 64 + lg * 16);
            #pragma unroll
            for (int ni = 0; ni < 4; ++ni)
                o[ni] = mfma16(pa, ldsfragR<256>(vb, ni * 16 + lr, ks * 64 + lg * 16), o[ni]);
        }
        cur ^= 1;
    }

    #pragma unroll
    for (int ni = 0; ni < 4; ++ni) {
        #pragma unroll
        for (int r = 0; r < 4; ++r) {
            int qr = q0 + w * 16 + lg * 4 + r;
            size_t rg = (size_t)b * 2048 + qr;
            int c = h * 64 + ni * 16 + lr;
            xcat[rg * 640 + c] = (bf16)o[ni][r];
        }
    }
}

// ---- out GEMM (BM=64 for occupancy: 320 blocks): d_out = xcat @ W_out + b_out
__global__ void __launch_bounds__(256) k_gemm_out(
    const bf16* __restrict__ X, const bf16* __restrict__ BT,
    const float* __restrict__ bout, float* __restrict__ out0)
{
    __shared__ __align__(16) bf16 lds[2 * (4096 + 8192)];   // 48 KB
    const int m0 = blockIdx.x * 64, n0 = blockIdx.y * 128;
    f32x4 acc[2][4];
    {
        f32x4 z = {0.f, 0.f, 0.f, 0.f};
        #pragma unroll
        for (int mi = 0; mi < 2; ++mi)
            #pragma unroll
            for (int ni = 0; ni < 4; ++ni) acc[mi][ni] = z;
    }
    gemm_main<2>(X, BT, m0, n0, lds, acc);

    const int tid = threadIdx.x, w = tid >> 6, lane = tid & 63;
    const int lr = lane & 15, lg = lane >> 4;
    const int wm = (w >> 1) * 32, wn = (w & 1) * 64;
    #pragma unroll
    for (int mi = 0; mi < 2; ++mi)
        #pragma unroll
        for (int ni = 0; ni < 4; ++ni) {
            int n = n0 + wn + ni * 16 + lr;
            float bv = bout[n];
            #pragma unroll
            for (int r = 0; r < 4; ++r) {
                int rg = m0 + wm + mi * 16 + lg * 4 + r;
                out0[(size_t)rg * 640 + n] = acc[mi][ni][r] + bv;
            }
        }
}

extern "C" void kernel_launch(void* const* d_in, const int* in_sizes, int n_in,
                              void* d_out, int out_size, void* d_ws, size_t ws_size,
                              hipStream_t stream)
{
    (void)in_sizes; (void)n_in; (void)out_size; (void)ws_size;
    const float* Q    = (const float*)d_in[0];
    const float* WQ   = (const float*)d_in[1];
    const float* bQ   = (const float*)d_in[2];
    const float* WK   = (const float*)d_in[3];
    const float* bK   = (const float*)d_in[4];
    const float* WV   = (const float*)d_in[5];
    const float* bV   = (const float*)d_in[6];
    const float* Wpos = (const float*)d_in[7];
    const float* Wagg = (const float*)d_in[8];
    const float* bagg = (const float*)d_in[9];
    const float* WO   = (const float*)d_in[10];
    const float* bout = (const float*)d_in[11];

    float* out0  = (float*)d_out;
    float* gattn = out0 + (size_t)MROWS * DIMN;   // attn output region (268 MB)

    char* ws = (char*)d_ws;
    bf16* Qbf    = (bf16*)(ws);                 ws += (size_t)MROWS * DIMN * 2;      // 5.24 MB
    bf16* BTqkv  = (bf16*)(ws);                 ws += (size_t)1920 * 640 * 2;        // 2.46 MB
    bf16* BTout  = (bf16*)(ws);                 ws += (size_t)640 * 640 * 2;         // 0.82 MB
    bf16* qsbuf  = (bf16*)(ws);                 ws += (size_t)4 * 8 * 2048 * 64 * 2; // 8 MB (q+k)
    bf16* vsT    = (bf16*)(ws);                 ws += (size_t)16 * 64 * 2048 * 2;    // 4 MB
    float* aggbuf= (float*)(ws);                ws += (size_t)3 * MROWS * AGGD * 4;  // 6 MB
    bf16* xcat   = (bf16*)(ws);                 ws += (size_t)MROWS * DIMN * 2;      // 5.24 MB

    k_split_q<<<dim3(2560), dim3(256), 0, stream>>>(Q, Qbf);
    k_prep_w<<<dim3(100, 4), dim3(256), 0, stream>>>(WQ, WK, WV, WO, BTqkv, BTout);
    k_gemm_qkv<<<dim3(32, 15), dim3(256), 0, stream>>>(Qbf, BTqkv,
                                                       bQ, bK, bV, Wpos, qsbuf, vsT, aggbuf);
    k_agg<<<dim3(128), dim3(256), 0, stream>>>(aggbuf, Wagg, bagg, xcat);
    k_attn<<<dim3(32, 16), dim3(256), 0, stream>>>(qsbuf, vsT, gattn, xcat);
    k_gemm_out<<<dim3(64, 5), dim3(256), 0, stream>>>(xcat, BTout, bout, out0);
}